// Round 9
// baseline (135.719 us; speedup 1.0000x reference)
//
#include <hip/hip_runtime.h>

typedef __attribute__((ext_vector_type(4))) float v4f;
typedef __attribute__((ext_vector_type(8))) short v8s;

// Problem constants
#define BB 2
#define SS 2048
#define DD 768
#define HH 12
#define HDIM 64
#define NWORDS 8          // 512 hash bits = 8 u64
#define HAM_MAX 179       // sim > 0.3  <=>  hamming <= 179

// ws layout (bytes), total ~68.1 MB
#define OFF_QBF    ((size_t)0)             // q,k,v bf16 contiguous 3x6291456
#define OFF_CTX    ((size_t)18874368)      // ctx f32 12582912
#define OFF_HSBF   ((size_t)31457280)      // 6291456
#define OFF_TFBF   ((size_t)37748736)      // 1048576
#define OFF_CTXBF  ((size_t)38797312)      // 6291456
#define OFF_CTX2BF ((size_t)45088768)      // 6291456
#define OFF_WTQKV  ((size_t)51380224)      // 3538944
#define OFF_WGT    ((size_t)54919168)      // 1376256
#define OFF_WOT    ((size_t)56295424)      // 1179648
#define OFF_HPWT   ((size_t)57475072)      // 917504
#define OFF_PROJ   ((size_t)58392576)      // 8388608
#define OFF_CODES  ((size_t)66781184)      // 262144
#define OFF_KEEP   ((size_t)67043328)      // 1048576
#define OFF_CMASK  ((size_t)68091904)      // 256

__device__ inline short f2bf(float x) {
    unsigned u = __float_as_uint(x);
    u = (u + 0x7FFFu + ((u >> 16) & 1u)) >> 16;  // RNE
    return (short)u;
}

// async global->LDS, 16B per lane, wave-uniform LDS base + lane*16
__device__ __forceinline__ void load_lds16(const void* g, void* l) {
    __builtin_amdgcn_global_load_lds((const __attribute__((address_space(1))) void*)g,
                                     (__attribute__((address_space(3))) void*)l,
                                     16, 0, 0);
}

// ---------------------------------------------------------------------------
// Convert activations f32 -> bf16 (hs and tf in one launch)
__global__ __launch_bounds__(256) void conv_act(
    const float* __restrict__ a, int na8, const float* __restrict__ b, int nb8,
    short* __restrict__ oa, short* __restrict__ ob) {
    int i = blockIdx.x * 256 + threadIdx.x;
    if (i >= na8 + nb8) return;
    const float* src; short* dst; int off;
    if (i < na8) { src = a; dst = oa; off = i << 3; }
    else         { src = b; dst = ob; off = (i - na8) << 3; }
    float4 x = *(const float4*)(src + off);
    float4 y = *(const float4*)(src + off + 4);
    v8s r;
    r[0] = f2bf(x.x); r[1] = f2bf(x.y); r[2] = f2bf(x.z); r[3] = f2bf(x.w);
    r[4] = f2bf(y.x); r[5] = f2bf(y.y); r[6] = f2bf(y.z); r[7] = f2bf(y.w);
    *(v8s*)(dst + off) = r;
}

// ---------------------------------------------------------------------------
// Transpose-convert W[Kd][Nd] f32 -> Wt[Nd][Kd] bf16 (32x32 LDS tiles)
__global__ __launch_bounds__(256) void tconvW(const float* __restrict__ W,
                                              short* __restrict__ Wt,
                                              int Kd, int Nd) {
    __shared__ float T[32][33];
    int n0 = blockIdx.x * 32, k0 = blockIdx.y * 32;
    int tx = threadIdx.x & 31, ty = threadIdx.x >> 5;
#pragma unroll
    for (int p = 0; p < 4; ++p) {
        int kk = ty + p * 8;
        T[tx][kk] = W[(size_t)(k0 + kk) * Nd + n0 + tx];
    }
    __syncthreads();
#pragma unroll
    for (int p = 0; p < 4; ++p) {
        int nn = ty + p * 8;
        Wt[(size_t)(n0 + nn) * Kd + k0 + tx] = f2bf(T[nn][tx]);
    }
}

// Same, for Wq/Wk/Wv -> contiguous WtQKV (z selects)
__global__ __launch_bounds__(256) void tconv3(const float* __restrict__ W0,
                                              const float* __restrict__ W1,
                                              const float* __restrict__ W2,
                                              short* __restrict__ Wt) {
    __shared__ float T[32][33];
    const float* W = (blockIdx.z == 0) ? W0 : (blockIdx.z == 1) ? W1 : W2;
    short* Wo = Wt + (size_t)blockIdx.z * 768 * 768;
    int n0 = blockIdx.x * 32, k0 = blockIdx.y * 32;
    int tx = threadIdx.x & 31, ty = threadIdx.x >> 5;
#pragma unroll
    for (int p = 0; p < 4; ++p) {
        int kk = ty + p * 8;
        T[tx][kk] = W[(size_t)(k0 + kk) * 768 + n0 + tx];
    }
    __syncthreads();
#pragma unroll
    for (int p = 0; p < 4; ++p) {
        int nn = ty + p * 8;
        Wo[(size_t)(n0 + nn) * 768 + k0 + tx] = f2bf(T[nn][tx]);
    }
}

// ---------------------------------------------------------------------------
// Build transposed hash-projection weight in bf16: hpwT[hc][kk], kk in [0,896)
__global__ __launch_bounds__(256) void build_hpwT(const float* __restrict__ hp,
                                                  short* __restrict__ hpwT) {
    __shared__ float T[32][33];
    int kk0 = blockIdx.x * 32, hc0 = blockIdx.y * 32;
    int h = hc0 >> 6, cb = hc0 & 63;
    int tx = threadIdx.x & 31, ty = threadIdx.x >> 5;
#pragma unroll
    for (int p = 0; p < 4; ++p) {
        int kp = ty + p * 8;
        int gk = kk0 + kp;
        int ks = (gk >= 768) ? gk - 768 : gk;
        float f = hp[((size_t)h * 768 + ks) * 64 + cb + tx];
        T[tx][kp] = (gk >= 768) ? 0.1f * f : f;
    }
    __syncthreads();
#pragma unroll
    for (int p = 0; p < 4; ++p) {
        int cp = ty + p * 8;
        hpwT[(size_t)(hc0 + cp) * 896 + kk0 + tx] = f2bf(T[cp][tx]);
    }
}

// ---------------------------------------------------------------------------
// MFMA bf16 GEMM, 3-buffer depth-2 pipeline with COUNTED vmcnt (T3/T4):
//   prologue: STAGE(b0,t0); STAGE(b1,t1);
//   iter kt:  s_waitcnt vmcnt(6) [vmcnt(0) on last] -> only buf[cur]'s loads
//             s_barrier; sched_barrier(0);
//             ds_read+MFMA on buf[cur];  STAGE(buf[cur+2], t+2).
// Next-tile loads stay in flight ACROSS the barrier (never drained to 0
// mid-loop). Buffer-reuse safe: STAGE targets buf[(kt-1)%3]; all waves'
// reads of it completed before they passed this iteration's barrier.
// BM=128, BN=WN*32, 4 waves (2x2), 16x16x32 MFMA, f32 acc. Linear LDS +
// global_load_lds(16) + XOR source-pre-swizzle (conflict-free, r5-r8).
// mode 0: f32 store (+bias);  mode 1: QKV scatter bf16;  mode 2: gate blend;
// mode 3: combined QKV+proj dispatch (bx<36 QKV, bx>=36 proj).
template<int WN>
__global__ __launch_bounds__(256) void gemm_mfma(
    const short* __restrict__ A, const short* __restrict__ A2,
    const short* __restrict__ Bt, const short* __restrict__ Bt2,
    const float* __restrict__ bias,
    float* __restrict__ outF, short* __restrict__ outB,
    int N, int K1, int K2, int mode, int nsub,
    const float* __restrict__ gctx, const float* __restrict__ ghs) {
    constexpr int BN = WN * 32;
    constexpr int ABYTES = 128 * 128;       // bytes per A buffer (128x64 bf16)
    constexpr int BBYTES = BN * 128;        // bytes per B buffer
    __shared__ __align__(16) short As[3][128 * 64];
    __shared__ __align__(16) short Bs[3][BN * 64];
    const int t = threadIdx.x;
    const int lane = t & 63, wave = t >> 6;
    const int wm = wave >> 1, wn = wave & 1;
    const int l15 = lane & 15, l4 = lane >> 4;
    const int bx = blockIdx.x;
    const int row0 = blockIdx.y * 128;

    // per-block routing
    int which, col0, myMode, Kblk, Nn = N;
    const short* Bp;
    const float* biasp = bias;
    if (mode == 3) {
        if (bx < 36) {
            which = bx / 12; col0 = (bx % 12) * 64; myMode = 1;
            Kblk = K1; Bp = Bt + (size_t)which * 589824; biasp = nullptr;
        } else {
            which = 3; col0 = (bx - 36) * 64; myMode = 0;
            Kblk = K1 + K2; Bp = Bt2; Nn = 512;
        }
    } else {
        which = bx / nsub; col0 = (bx % nsub) * BN; myMode = mode;
        Kblk = K1 + K2; Bp = Bt + (size_t)which * 589824;
    }

    // source swizzle: lane covers row (chunk*8 + lane>>3), 16B slot (lane&7)
    const int lrow = lane >> 3;
    const int scolS = ((lane & 7) ^ lrow) << 3;     // swizzled col offset in shorts

    auto STAGE = [&](int buf, int k0) {
        const short* Ap; int ks, strideS;
        if (k0 < K1) { Ap = A;  ks = k0;      strideS = K1; }
        else         { Ap = A2; ks = k0 - K1; strideS = K2; }
#pragma unroll
        for (int qq = 0; qq < 4; ++qq) {
            int c = wave * 4 + qq;                   // A chunk: rows 8c..8c+7
            const short* ga = Ap + (size_t)(row0 + c * 8 + lrow) * strideS + ks + scolS;
            load_lds16(ga, (char*)As + buf * ABYTES + c * 1024);
        }
#pragma unroll
        for (int qq = 0; qq < WN; ++qq) {
            int c = wave * WN + qq;                  // B chunk
            const short* gb = Bp + (size_t)(col0 + c * 8 + lrow) * Kblk + k0 + scolS;
            load_lds16(gb, (char*)Bs + buf * BBYTES + c * 1024);
        }
    };

    v4f acc[4][WN];
#pragma unroll
    for (int m = 0; m < 4; ++m)
#pragma unroll
        for (int n = 0; n < WN; ++n) acc[m][n] = (v4f){0.f, 0.f, 0.f, 0.f};

    const int nK = Kblk >> 6;
    STAGE(0, 0);
    STAGE(1, 64);
    int cur = 0;
    for (int kt = 0; kt < nK; ++kt) {
        // wait ONLY buf[cur]'s 6 loads (6 more stay in flight), except last iter
        if (kt < nK - 1) asm volatile("s_waitcnt vmcnt(6)" ::: "memory");
        else             asm volatile("s_waitcnt vmcnt(0)" ::: "memory");
        __builtin_amdgcn_s_barrier();
        __builtin_amdgcn_sched_barrier(0);
#pragma unroll
        for (int kk = 0; kk < 2; ++kk) {
            v8s a[4], b[WN];
#pragma unroll
            for (int m = 0; m < 4; ++m) {
                int row = wm * 64 + m * 16 + l15;
                int byte = (row * 128 + kk * 64 + l4 * 16) ^ ((row & 7) << 4);
                a[m] = *(const v8s*)((const char*)As + cur * ABYTES + byte);
            }
#pragma unroll
            for (int n = 0; n < WN; ++n) {
                int row = wn * (WN * 16) + n * 16 + l15;
                int byte = (row * 128 + kk * 64 + l4 * 16) ^ ((row & 7) << 4);
                b[n] = *(const v8s*)((const char*)Bs + cur * BBYTES + byte);
            }
#pragma unroll
            for (int m = 0; m < 4; ++m)
#pragma unroll
                for (int n = 0; n < WN; ++n)
                    acc[m][n] = __builtin_amdgcn_mfma_f32_16x16x32_bf16(a[m], b[n], acc[m][n], 0, 0, 0);
        }
        if (kt + 2 < nK) {
            int nb = cur + 2; if (nb >= 3) nb -= 3;
            STAGE(nb, (kt + 2) << 6);
        }
        cur = (cur == 2) ? 0 : cur + 1;
    }
#pragma unroll
    for (int m = 0; m < 4; ++m) {
#pragma unroll
        for (int n = 0; n < WN; ++n) {
            int gr0 = row0 + (wm * 4 + m) * 16 + l4 * 4;
            int gc = col0 + (wn * WN + n) * 16 + l15;
#pragma unroll
            for (int i = 0; i < 4; ++i) {
                int gr = gr0 + i;
                float c = acc[m][n][i];
                if (myMode == 0) {
                    if (biasp) c += biasp[gc];
                    outF[(size_t)gr * Nn + gc] = c;
                } else if (myMode == 1) {
                    int bb = gr >> 11, s = gr & 2047;
                    int h = gc >> 6, hd = gc & 63;
                    outB[(size_t)which * 3145728 +
                         (((size_t)(bb * HH + h)) * SS + s) * HDIM + hd] = f2bf(c);
                } else {
                    c += biasp[gc];
                    float g = 1.f / (1.f + __expf(-c));
                    size_t off = (size_t)gr * Nn + gc;
                    outB[off] = f2bf(g * gctx[off] + (1.f - g) * ghs[off]);
                }
            }
        }
    }
}

// ---------------------------------------------------------------------------
// Pack sign bits of proj[4096][512] into codes[4096][8] u64 via wave ballot.
// Block 0 also zero-inits the chunkmask bitmap.
__global__ __launch_bounds__(512) void pack_codes(const float* __restrict__ proj,
                                                  unsigned long long* __restrict__ codes,
                                                  unsigned int* __restrict__ cmask) {
    int row = blockIdx.x, t = threadIdx.x;
    if (row == 0 && t < 64) cmask[t] = 0u;
    float v = proj[(size_t)row * 512 + t];
    unsigned long long bal = __ballot(v > 0.f);
    if ((t & 63) == 0) codes[(size_t)row * NWORDS + (t >> 6)] = bal;
}

// ---------------------------------------------------------------------------
// LSH keep masks: one (qchunk, kchunk, b) tile per block, 2048 blocks.
__global__ __launch_bounds__(256) void mask_kernel(
    const unsigned long long* __restrict__ codes, const int* __restrict__ mask,
    unsigned long long* __restrict__ keepArr, unsigned int* __restrict__ chunkmask) {
    __shared__ unsigned long long ckS[64][NWORDS];
    __shared__ int mskS[64];
    const int t = threadIdx.x;
    const int r = t >> 2, tx = t & 3;
    const int qc = blockIdx.x, kc = blockIdx.y, b = blockIdx.z;
    const int q0 = qc << 6, k0 = kc << 6;

#pragma unroll
    for (int p = 0; p < 2; ++p) {
        int idx = t + (p << 8);
        int jr = idx >> 3, ww = idx & 7;
        ckS[jr][ww ^ (jr >> 4)] =
            codes[((size_t)(b * SS + k0 + jr)) * NWORDS + ww];
    }
    if (t < 64) mskS[t] = mask[b * SS + k0 + t];
    unsigned long long cq[NWORDS];
    {
        const unsigned long long* cp = codes + ((size_t)(b * SS + q0 + r)) * NWORDS;
#pragma unroll
        for (int w = 0; w < NWORDS; ++w) cq[w] = cp[w];
    }
    __syncthreads();

    unsigned long long k64 = 0;
#pragma unroll
    for (int j16 = 0; j16 < 16; ++j16) {
        int j = (tx << 4) + j16;
        int ham = 0;
#pragma unroll
        for (int w = 0; w < NWORDS; ++w)
            ham += __popcll(cq[w] ^ ckS[j][w ^ tx]);
        if (ham <= HAM_MAX && mskS[j]) k64 |= 1ull << j;
    }
    k64 |= __shfl_xor(k64, 1, 4);
    k64 |= __shfl_xor(k64, 2, 4);
    if (tx == 0) keepArr[((size_t)(b * SS + q0 + r)) * 32 + kc] = k64;
    if (__syncthreads_or(k64 != 0) && t == 0)
        atomicOr(&chunkmask[b * 32 + qc], 1u << kc);
}

// ---------------------------------------------------------------------------
// MFMA flash attention over active chunks only. bf16 Q/K/V.
// 4 waves; wave w owns score/output rows w*16..w*16+15 (same C-layout for
// QK^T and PV -> softmax stats stay lane-local: row = l4*4+i).
__global__ __launch_bounds__(256) void attn_kernel(
    const short* __restrict__ qm, const short* __restrict__ km,
    const short* __restrict__ vm, const unsigned long long* __restrict__ keepArr,
    const unsigned int* __restrict__ chunkmask, float* __restrict__ ctx,
    short* __restrict__ ctxbf) {
    __shared__ __align__(16) short Qs[64][72];
    __shared__ __align__(16) short Ks[64][72];
    __shared__ __align__(16) short VT[64][72];   // V transposed: [dim][key]
    __shared__ __align__(16) short Ps[64][72];
    __shared__ unsigned long long keepS[64];
    const int t = threadIdx.x;
    const int lane = t & 63, wave = t >> 6;
    const int l15 = lane & 15, l4 = lane >> 4;
    const int q0 = blockIdx.x << 6;
    const int bh = blockIdx.y;
    const int b = bh / HH, h = bh % HH;

    {   // stage Q (direct bf16 copy)
        int r = t >> 2, seg = t & 3;
        const short* g = qm + ((size_t)bh * SS + q0 + r) * HDIM + seg * 16;
        *(int4*)&Qs[r][seg * 16] = *(const int4*)g;
        *(int4*)&Qs[r][seg * 16 + 8] = *(const int4*)(g + 8);
    }
    unsigned int cm = chunkmask[b * 32 + blockIdx.x];
    float mrun[4], lrun[4];
    v4f oacc[4];
#pragma unroll
    for (int i = 0; i < 4; ++i) { mrun[i] = -1e30f; lrun[i] = 0.f; }
#pragma unroll
    for (int n = 0; n < 4; ++n) oacc[n] = (v4f){0.f, 0.f, 0.f, 0.f};

    while (cm) {
        int kc = __ffs(cm) - 1;
        cm &= cm - 1;
        __syncthreads();   // prev chunk's reads done (1st iter: nothing)
        if (t < 64) keepS[t] = keepArr[((size_t)(b * SS + q0 + t)) * 32 + kc];
        {   // stage K rows + V transposed
            int key = t >> 2, seg = t & 3;
            const short* gk = km + ((size_t)bh * SS + (kc << 6) + key) * HDIM + seg * 16;
            *(int4*)&Ks[key][seg * 16] = *(const int4*)gk;
            *(int4*)&Ks[key][seg * 16 + 8] = *(const int4*)(gk + 8);
            const short* gv = vm + ((size_t)bh * SS + (kc << 6) + key) * HDIM + seg * 16;
            int4 v0 = *(const int4*)gv, v1 = *(const int4*)(gv + 8);
            const short* s0 = (const short*)&v0;
            const short* s1 = (const short*)&v1;
#pragma unroll
            for (int e = 0; e < 8; ++e) VT[seg * 16 + e][key] = s0[e];
#pragma unroll
            for (int e = 0; e < 8; ++e) VT[seg * 16 + 8 + e][key] = s1[e];
        }
        __syncthreads();

        // QK^T: S[64 rows][64 keys], wave computes 16 rows x 64 keys
        v8s qa0 = *(const v8s*)&Qs[wave * 16 + l15][l4 * 8];
        v8s qa1 = *(const v8s*)&Qs[wave * 16 + l15][32 + l4 * 8];
        v4f sacc[4];
#pragma unroll
        for (int n = 0; n < 4; ++n) sacc[n] = (v4f){0.f, 0.f, 0.f, 0.f};
#pragma unroll
        for (int n = 0; n < 4; ++n) {
            v8s kb0 = *(const v8s*)&Ks[n * 16 + l15][l4 * 8];
            v8s kb1 = *(const v8s*)&Ks[n * 16 + l15][32 + l4 * 8];
            sacc[n] = __builtin_amdgcn_mfma_f32_16x16x32_bf16(qa0, kb0, sacc[n], 0, 0, 0);
            sacc[n] = __builtin_amdgcn_mfma_f32_16x16x32_bf16(qa1, kb1, sacc[n], 0, 0, 0);
        }
        // online softmax; row r = wave*16 + l4*4 + i lives in component i
        unsigned long long kp[4];
#pragma unroll
        for (int i = 0; i < 4; ++i) kp[i] = keepS[wave * 16 + l4 * 4 + i];
        float pe[4][4], mloc[4];
#pragma unroll
        for (int i = 0; i < 4; ++i) mloc[i] = -1e30f;
#pragma unroll
        for (int n = 0; n < 4; ++n)
#pragma unroll
            for (int i = 0; i < 4; ++i) {
                bool keep = (kp[i] >> (n * 16 + l15)) & 1;
                float sv = keep ? sacc[n][i] * 0.125f : -1e30f;
                pe[n][i] = sv;
                mloc[i] = fmaxf(mloc[i], sv);
            }
#pragma unroll
        for (int i = 0; i < 4; ++i) {
            mloc[i] = fmaxf(mloc[i], __shfl_xor(mloc[i], 1, 16));
            mloc[i] = fmaxf(mloc[i], __shfl_xor(mloc[i], 2, 16));
            mloc[i] = fmaxf(mloc[i], __shfl_xor(mloc[i], 4, 16));
            mloc[i] = fmaxf(mloc[i], __shfl_xor(mloc[i], 8, 16));
        }
        float psum[4] = {0.f, 0.f, 0.f, 0.f};
#pragma unroll
        for (int n = 0; n < 4; ++n)
#pragma unroll
            for (int i = 0; i < 4; ++i) {
                bool keep = pe[n][i] > -1e29f;
                float mnew = fmaxf(mrun[i], mloc[i]);
                float p = keep ? __expf(pe[n][i] - mnew) : 0.f;
                pe[n][i] = p;
                psum[i] += p;
            }
#pragma unroll
        for (int i = 0; i < 4; ++i) {
            psum[i] += __shfl_xor(psum[i], 1, 16);
            psum[i] += __shfl_xor(psum[i], 2, 16);
            psum[i] += __shfl_xor(psum[i], 4, 16);
            psum[i] += __shfl_xor(psum[i], 8, 16);
            float mnew = fmaxf(mrun[i], mloc[i]);
            float scale = __expf(mrun[i] - mnew);
            lrun[i] = lrun[i] * scale + psum[i];
            mrun[i] = mnew;
#pragma unroll
            for (int n = 0; n < 4; ++n) oacc[n][i] *= scale;
        }
        // P -> bf16 LDS (C-layout write)
#pragma unroll
        for (int n = 0; n < 4; ++n)
#pragma unroll
            for (int i = 0; i < 4; ++i)
                Ps[wave * 16 + l4 * 4 + i][n * 16 + l15] = f2bf(pe[n][i]);
        __syncthreads();

        // PV: out += P[16 rows x 64 keys] * V[64 keys x 64 dims]
        v8s pa0 = *(const v8s*)&Ps[wave * 16 + l15][l4 * 8];
        v8s pa1 = *(const v8s*)&Ps[wave * 16 + l15][32 + l4 * 8];
#pragma unroll
        for (int n = 0; n < 4; ++n) {
            v8s vb0 = *(const v8s*)&VT[n * 16 + l15][l4 * 8];
            v8s vb1 = *(const v8s*)&VT[n * 16 + l15][32 + l4 * 8];
            oacc[n] = __builtin_amdgcn_mfma_f32_16x16x32_bf16(pa0, vb0, oacc[n], 0, 0, 0);
            oacc[n] = __builtin_amdgcn_mfma_f32_16x16x32_bf16(pa1, vb1, oacc[n], 0, 0, 0);
        }
    }
    float invl[4];
#pragma unroll
    for (int i = 0; i < 4; ++i) invl[i] = lrun[i] > 0.f ? 1.f / lrun[i] : 0.f;
#pragma unroll
    for (int n = 0; n < 4; ++n)
#pragma unroll
        for (int i = 0; i < 4; ++i) {
            int r = wave * 16 + l4 * 4 + i;
            size_t off = ((size_t)b * SS + q0 + r) * DD + h * HDIM + n * 16 + l15;
            float val = oacc[n][i] * invl[i];
            ctx[off] = val;
            ctxbf[off] = f2bf(val);
        }
}

// ---------------------------------------------------------------------------
extern "C" void kernel_launch(void* const* d_in, const int* in_sizes, int n_in,
                              void* d_out, int out_size, void* d_ws, size_t ws_size,
                              hipStream_t stream) {
    const float* hs = (const float*)d_in[0];
    const float* tf = (const float*)d_in[1];
    const float* Wq = (const float*)d_in[2];
    const float* Wk = (const float*)d_in[3];
    const float* Wv = (const float*)d_in[4];
    const float* Wo = (const float*)d_in[5];
    const float* bo = (const float*)d_in[6];
    const float* Wg = (const float*)d_in[7];
    const float* bg = (const float*)d_in[8];
    const float* hp = (const float*)d_in[9];
    const float* tb = (const float*)d_in[10];
    const int* msk  = (const int*)d_in[11];
    float* out = (float*)d_out;

    char* w = (char*)d_ws;
    short* qkvbf  = (short*)(w + OFF_QBF);
    float* ctx    = (float*)(w + OFF_CTX);
    short* hsbf   = (short*)(w + OFF_HSBF);
    short* tfbf   = (short*)(w + OFF_TFBF);
    short* ctxbf  = (short*)(w + OFF_CTXBF);
    short* ctx2bf = (short*)(w + OFF_CTX2BF);
    short* wtqkv  = (short*)(w + OFF_WTQKV);
    short* wgT    = (short*)(w + OFF_WGT);
    short* woT    = (short*)(w + OFF_WOT);
    short* hpwT   = (short*)(w + OFF_HPWT);
    float* proj   = (float*)(w + OFF_PROJ);
    unsigned long long* codes = (unsigned long long*)(w + OFF_CODES);
    unsigned long long* keepA = (unsigned long long*)(w + OFF_KEEP);
    unsigned int* cmask = (unsigned int*)(w + OFF_CMASK);

    // 1. activations -> bf16
    conv_act<<<dim3((3145728 / 8 + 524288 / 8 + 255) / 256), 256, 0, stream>>>(
        hs, 3145728 / 8, tf, 524288 / 8, hsbf, tfbf);
    // 2-4. weights -> transposed bf16
    tconv3<<<dim3(24, 24, 3), 256, 0, stream>>>(Wq, Wk, Wv, wtqkv);
    tconvW<<<dim3(24, 28), 256, 0, stream>>>(Wg, wgT, 896, 768);
    tconvW<<<dim3(24, 24), 256, 0, stream>>>(Wo, woT, 768, 768);
    build_hpwT<<<dim3(28, 16), 256, 0, stream>>>(hp, hpwT);
    // 5. COMBINED QKV + LSH-projection dispatch (mode 3):
    //    bx 0-35: QKV -> bf16 [B,H,S,HD] x3;  bx 36-43: proj -> f32 + bias
    gemm_mfma<2><<<dim3(44, 32), 256, 0, stream>>>(
        hsbf, tfbf, wtqkv, hpwT, tb, proj, qkvbf, 512, 768, 128, 3, 12, nullptr, nullptr);
    // 6-8. codes (+cmask zero), masks, attention
    pack_codes<<<4096, 512, 0, stream>>>(proj, codes, cmask);
    mask_kernel<<<dim3(32, 32, 2), 256, 0, stream>>>(codes, msk, keepA, cmask);
    attn_kernel<<<dim3(32, 24), 256, 0, stream>>>(
        qkvbf, qkvbf + 3145728, qkvbf + 2 * 3145728, keepA, cmask, ctx, ctxbf);
    // 9. gate GEMM + sigmoid-blend epilogue -> ctx2 bf16
    gemm_mfma<2><<<dim3(12, 32), 256, 0, stream>>>(
        ctxbf, tfbf, wgT, nullptr, bg, nullptr, ctx2bf, 768, 768, 128, 2, 12, ctx, hs);
    // 10. output projection -> d_out f32
    gemm_mfma<2><<<dim3(12, 32), 256, 0, stream>>>(
        ctx2bf, nullptr, woT, nullptr, bo, out, nullptr, 768, 768, 0, 0, 12, nullptr, nullptr);
}

// Round 10
// 122.097 us; speedup vs baseline: 1.1116x; 1.1116x over previous
//
#include <hip/hip_runtime.h>

typedef __attribute__((ext_vector_type(4))) float v4f;
typedef __attribute__((ext_vector_type(8))) short v8s;

// Problem constants
#define BB 2
#define SS 2048
#define DD 768
#define HH 12
#define HDIM 64
#define NWORDS 8          // 512 hash bits = 8 u64
#define HAM_MAX 179       // sim > 0.3  <=>  hamming <= 179

// ws layout (bytes), total ~68.1 MB
#define OFF_QBF    ((size_t)0)             // q,k,v bf16 contiguous 3x6291456
#define OFF_CTX    ((size_t)18874368)      // ctx f32 12582912
#define OFF_HSBF   ((size_t)31457280)      // 6291456
#define OFF_TFBF   ((size_t)37748736)      // 1048576
#define OFF_CTXBF  ((size_t)38797312)      // 6291456
#define OFF_CTX2BF ((size_t)45088768)      // 6291456
#define OFF_WTQKV  ((size_t)51380224)      // 3538944
#define OFF_WGT    ((size_t)54919168)      // 1376256
#define OFF_WOT    ((size_t)56295424)      // 1179648
#define OFF_HPWT   ((size_t)57475072)      // 917504
#define OFF_PROJ   ((size_t)58392576)      // 8388608
#define OFF_CODES  ((size_t)66781184)      // 262144
#define OFF_KEEP   ((size_t)67043328)      // 1048576
#define OFF_CMASK  ((size_t)68091904)      // 256

__device__ inline short f2bf(float x) {
    unsigned u = __float_as_uint(x);
    u = (u + 0x7FFFu + ((u >> 16) & 1u)) >> 16;  // RNE
    return (short)u;
}

// async global->LDS, 16B per lane, wave-uniform LDS base + lane*16
__device__ __forceinline__ void load_lds16(const void* g, void* l) {
    __builtin_amdgcn_global_load_lds((const __attribute__((address_space(1))) void*)g,
                                     (__attribute__((address_space(3))) void*)l,
                                     16, 0, 0);
}

// ---------------------------------------------------------------------------
// Fused preprocessing: one dispatch, block-range routing.
//   [0,1792)        : conv_act (hs,tf -> bf16)
//   [1792,3520)     : tconv3  (Wq/Wk/Wv -> WtQKV transposed bf16)
//   [3520,4192)     : tconvW  Wg (896x768 -> wgT)
//   [4192,4768)     : tconvW  Wo (768x768 -> woT)
//   [4768,5216)     : build_hpwT
__global__ __launch_bounds__(256) void prep(
    const float* __restrict__ hs, const float* __restrict__ tf,
    const float* __restrict__ Wq, const float* __restrict__ Wk,
    const float* __restrict__ Wv, const float* __restrict__ Wg,
    const float* __restrict__ Wo, const float* __restrict__ hp,
    short* __restrict__ hsbf, short* __restrict__ tfbf,
    short* __restrict__ wtqkv, short* __restrict__ wgT,
    short* __restrict__ woT, short* __restrict__ hpwT) {
    __shared__ float T[32][33];
    const int blk = blockIdx.x;
    const int tid = threadIdx.x;
    if (blk < 1792) {
        // conv_act: 8 floats per thread
        int i = blk * 256 + tid;
        const int na8 = 3145728 / 8;
        const float* src; short* dst; int off;
        if (i < na8) { src = hs; dst = hsbf; off = i << 3; }
        else         { src = tf; dst = tfbf; off = (i - na8) << 3; }
        float4 x = *(const float4*)(src + off);
        float4 y = *(const float4*)(src + off + 4);
        v8s r;
        r[0] = f2bf(x.x); r[1] = f2bf(x.y); r[2] = f2bf(x.z); r[3] = f2bf(x.w);
        r[4] = f2bf(y.x); r[5] = f2bf(y.y); r[6] = f2bf(y.z); r[7] = f2bf(y.w);
        *(v8s*)(dst + off) = r;
        return;
    }
    const int tx = tid & 31, ty = tid >> 5;
    if (blk < 3520) {
        // tconv3: W[768][768] -> Wt[768][768] transposed, z selects weight
        int b = blk - 1792;
        int z = b / 576, rem = b % 576;
        int x = rem % 24, y = rem / 24;
        const float* W = (z == 0) ? Wq : (z == 1) ? Wk : Wv;
        short* Wt = wtqkv + (size_t)z * 589824;
        int n0 = x * 32, k0 = y * 32;
#pragma unroll
        for (int p = 0; p < 4; ++p) {
            int kk = ty + p * 8;
            T[tx][kk] = W[(size_t)(k0 + kk) * 768 + n0 + tx];
        }
        __syncthreads();
#pragma unroll
        for (int p = 0; p < 4; ++p) {
            int nn = ty + p * 8;
            Wt[(size_t)(n0 + nn) * 768 + k0 + tx] = f2bf(T[nn][tx]);
        }
    } else if (blk < 4192) {
        // tconvW Wg: [896][768] -> wgT[768][896]
        int b = blk - 3520;
        int x = b % 24, y = b / 24;
        int n0 = x * 32, k0 = y * 32;
#pragma unroll
        for (int p = 0; p < 4; ++p) {
            int kk = ty + p * 8;
            T[tx][kk] = Wg[(size_t)(k0 + kk) * 768 + n0 + tx];
        }
        __syncthreads();
#pragma unroll
        for (int p = 0; p < 4; ++p) {
            int nn = ty + p * 8;
            wgT[(size_t)(n0 + nn) * 896 + k0 + tx] = f2bf(T[nn][tx]);
        }
    } else if (blk < 4768) {
        // tconvW Wo: [768][768] -> woT[768][768]
        int b = blk - 4192;
        int x = b % 24, y = b / 24;
        int n0 = x * 32, k0 = y * 32;
#pragma unroll
        for (int p = 0; p < 4; ++p) {
            int kk = ty + p * 8;
            T[tx][kk] = Wo[(size_t)(k0 + kk) * 768 + n0 + tx];
        }
        __syncthreads();
#pragma unroll
        for (int p = 0; p < 4; ++p) {
            int nn = ty + p * 8;
            woT[(size_t)(n0 + nn) * 768 + k0 + tx] = f2bf(T[nn][tx]);
        }
    } else {
        // build_hpwT: hpwT[hc][kk], kk<768: hp[h][kk][c]; kk>=768: 0.1*hp[h][kk-768][c]
        int b = blk - 4768;
        int x = b % 28, y = b / 28;
        int kk0 = x * 32, hc0 = y * 32;
        int h = hc0 >> 6, cb = hc0 & 63;
#pragma unroll
        for (int p = 0; p < 4; ++p) {
            int kp = ty + p * 8;
            int gk = kk0 + kp;
            int ks = (gk >= 768) ? gk - 768 : gk;
            float f = hp[((size_t)h * 768 + ks) * 64 + cb + tx];
            T[tx][kp] = (gk >= 768) ? 0.1f * f : f;
        }
        __syncthreads();
#pragma unroll
        for (int p = 0; p < 4; ++p) {
            int cp = ty + p * 8;
            hpwT[(size_t)(hc0 + cp) * 896 + kk0 + tx] = f2bf(T[cp][tx]);
        }
    }
}

// ---------------------------------------------------------------------------
// MFMA bf16 GEMM, 2-phase prefetch double-buffer (r8 structure, proven) +
// XCD-aware bijective block swizzle: each XCD owns a contiguous chunk of 4
// A-row panels (4x196KB fits its private 4MB L2) -> A-loads become L2 hits.
// Requires gridDim.y==32 and total blocks % 8 == 0 (44x32, 12x32: exact).
// BM=128, BN=WN*32, 4 waves (2x2), 16x16x32 MFMA, f32 acc. Linear LDS +
// global_load_lds(16) + XOR source-pre-swizzle (conflict-free, r5-r9).
// mode 0: f32 store (+bias);  mode 1: QKV scatter bf16;  mode 2: gate blend;
// mode 3: combined QKV+proj dispatch (bx<36 QKV, bx>=36 proj).
template<int WN>
__global__ __launch_bounds__(256) void gemm_mfma(
    const short* __restrict__ A, const short* __restrict__ A2,
    const short* __restrict__ Bt, const short* __restrict__ Bt2,
    const float* __restrict__ bias,
    float* __restrict__ outF, short* __restrict__ outB,
    int N, int K1, int K2, int mode, int nsub,
    const float* __restrict__ gctx, const float* __restrict__ ghs) {
    constexpr int BN = WN * 32;
    __shared__ __align__(16) short As[2][128 * 64];   // 2 x 16 KB
    __shared__ __align__(16) short Bs[2][BN * 64];
    const int t = threadIdx.x;
    const int lane = t & 63, wave = t >> 6;
    const int wm = wave >> 1, wn = wave & 1;
    const int l15 = lane & 15, l4 = lane >> 4;

    // XCD-aware swizzle: flat%8 = XCD (round-robin dispatch); give each XCD
    // a contiguous run of by values so its L2 caches few A panels.
    const int nbx = gridDim.x;
    int flat = blockIdx.x + nbx * blockIdx.y;
    int xcd = flat & 7, j = flat >> 3;
    int by = xcd * 4 + j / nbx;          // gridDim.y == 32
    int bx = j % nbx;
    const int row0 = by * 128;

    // per-block routing
    int which, col0, myMode, Kblk, Nn = N;
    const short* Bp;
    const float* biasp = bias;
    if (mode == 3) {
        if (bx < 36) {
            which = bx / 12; col0 = (bx % 12) * 64; myMode = 1;
            Kblk = K1; Bp = Bt + (size_t)which * 589824; biasp = nullptr;
        } else {
            which = 3; col0 = (bx - 36) * 64; myMode = 0;
            Kblk = K1 + K2; Bp = Bt2; Nn = 512;
        }
    } else {
        which = bx / nsub; col0 = (bx % nsub) * BN; myMode = mode;
        Kblk = K1 + K2; Bp = Bt + (size_t)which * 589824;
    }

    // source swizzle: lane covers row (chunk*8 + lane>>3), 16B slot (lane&7)
    const int lrow = lane >> 3;
    const int scolS = ((lane & 7) ^ lrow) << 3;     // swizzled col offset in shorts

    auto STAGE = [&](int buf, int k0) {
        const short* Ap; int ks, strideS;
        if (k0 < K1) { Ap = A;  ks = k0;      strideS = K1; }
        else         { Ap = A2; ks = k0 - K1; strideS = K2; }
#pragma unroll
        for (int qq = 0; qq < 4; ++qq) {
            int c = wave * 4 + qq;                   // A chunk: rows 8c..8c+7
            const short* ga = Ap + (size_t)(row0 + c * 8 + lrow) * strideS + ks + scolS;
            load_lds16(ga, (char*)As + buf * 16384 + c * 1024);
        }
#pragma unroll
        for (int qq = 0; qq < WN; ++qq) {
            int c = wave * WN + qq;                  // B chunk
            const short* gb = Bp + (size_t)(col0 + c * 8 + lrow) * Kblk + k0 + scolS;
            load_lds16(gb, (char*)Bs + buf * (BN * 128) + c * 1024);
        }
    };

    v4f acc[4][WN];
#pragma unroll
    for (int m = 0; m < 4; ++m)
#pragma unroll
        for (int n = 0; n < WN; ++n) acc[m][n] = (v4f){0.f, 0.f, 0.f, 0.f};

    const int nK = Kblk >> 6;
    STAGE(0, 0);
    __syncthreads();                                 // drain vmcnt(0): tile 0 ready
    int cur = 0;
    for (int kt = 0; kt < nK; ++kt) {
        if (kt + 1 < nK) STAGE(cur ^ 1, (kt + 1) << 6);  // prefetch next tile
#pragma unroll
        for (int kk = 0; kk < 2; ++kk) {
            v8s a[4], b[WN];
#pragma unroll
            for (int m = 0; m < 4; ++m) {
                int row = wm * 64 + m * 16 + l15;
                int byte = (row * 128 + kk * 64 + l4 * 16) ^ ((row & 7) << 4);
                a[m] = *(const v8s*)((const char*)As + cur * 16384 + byte);
            }
#pragma unroll
            for (int n = 0; n < WN; ++n) {
                int row = wn * (WN * 16) + n * 16 + l15;
                int byte = (row * 128 + kk * 64 + l4 * 16) ^ ((row & 7) << 4);
                b[n] = *(const v8s*)((const char*)Bs + cur * (BN * 128) + byte);
            }
#pragma unroll
            for (int m = 0; m < 4; ++m)
#pragma unroll
                for (int n = 0; n < WN; ++n)
                    acc[m][n] = __builtin_amdgcn_mfma_f32_16x16x32_bf16(a[m], b[n], acc[m][n], 0, 0, 0);
        }
        __syncthreads();   // drains lgkmcnt (buf[cur] reads) + vmcnt (prefetch landed)
        cur ^= 1;
    }
#pragma unroll
    for (int m = 0; m < 4; ++m) {
#pragma unroll
        for (int n = 0; n < WN; ++n) {
            int gr0 = row0 + (wm * 4 + m) * 16 + l4 * 4;
            int gc = col0 + (wn * WN + n) * 16 + l15;
#pragma unroll
            for (int i = 0; i < 4; ++i) {
                int gr = gr0 + i;
                float c = acc[m][n][i];
                if (myMode == 0) {
                    if (biasp) c += biasp[gc];
                    outF[(size_t)gr * Nn + gc] = c;
                } else if (myMode == 1) {
                    int bb = gr >> 11, s = gr & 2047;
                    int h = gc >> 6, hd = gc & 63;
                    outB[(size_t)which * 3145728 +
                         (((size_t)(bb * HH + h)) * SS + s) * HDIM + hd] = f2bf(c);
                } else {
                    c += biasp[gc];
                    float g = 1.f / (1.f + __expf(-c));
                    size_t off = (size_t)gr * Nn + gc;
                    outB[off] = f2bf(g * gctx[off] + (1.f - g) * ghs[off]);
                }
            }
        }
    }
}

// ---------------------------------------------------------------------------
// Pack sign bits of proj[4096][512] into codes[4096][8] u64 via wave ballot.
// Block 0 also zero-inits the chunkmask bitmap.
__global__ __launch_bounds__(512) void pack_codes(const float* __restrict__ proj,
                                                  unsigned long long* __restrict__ codes,
                                                  unsigned int* __restrict__ cmask) {
    int row = blockIdx.x, t = threadIdx.x;
    if (row == 0 && t < 64) cmask[t] = 0u;
    float v = proj[(size_t)row * 512 + t];
    unsigned long long bal = __ballot(v > 0.f);
    if ((t & 63) == 0) codes[(size_t)row * NWORDS + (t >> 6)] = bal;
}

// ---------------------------------------------------------------------------
// LSH keep masks: one (qchunk, kchunk, b) tile per block, 2048 blocks.
__global__ __launch_bounds__(256) void mask_kernel(
    const unsigned long long* __restrict__ codes, const int* __restrict__ mask,
    unsigned long long* __restrict__ keepArr, unsigned int* __restrict__ chunkmask) {
    __shared__ unsigned long long ckS[64][NWORDS];
    __shared__ int mskS[64];
    const int t = threadIdx.x;
    const int r = t >> 2, tx = t & 3;
    const int qc = blockIdx.x, kc = blockIdx.y, b = blockIdx.z;
    const int q0 = qc << 6, k0 = kc << 6;

#pragma unroll
    for (int p = 0; p < 2; ++p) {
        int idx = t + (p << 8);
        int jr = idx >> 3, ww = idx & 7;
        ckS[jr][ww ^ (jr >> 4)] =
            codes[((size_t)(b * SS + k0 + jr)) * NWORDS + ww];
    }
    if (t < 64) mskS[t] = mask[b * SS + k0 + t];
    unsigned long long cq[NWORDS];
    {
        const unsigned long long* cp = codes + ((size_t)(b * SS + q0 + r)) * NWORDS;
#pragma unroll
        for (int w = 0; w < NWORDS; ++w) cq[w] = cp[w];
    }
    __syncthreads();

    unsigned long long k64 = 0;
#pragma unroll
    for (int j16 = 0; j16 < 16; ++j16) {
        int j = (tx << 4) + j16;
        int ham = 0;
#pragma unroll
        for (int w = 0; w < NWORDS; ++w)
            ham += __popcll(cq[w] ^ ckS[j][w ^ tx]);
        if (ham <= HAM_MAX && mskS[j]) k64 |= 1ull << j;
    }
    k64 |= __shfl_xor(k64, 1, 4);
    k64 |= __shfl_xor(k64, 2, 4);
    if (tx == 0) keepArr[((size_t)(b * SS + q0 + r)) * 32 + kc] = k64;
    if (__syncthreads_or(k64 != 0) && t == 0)
        atomicOr(&chunkmask[b * 32 + qc], 1u << kc);
}

// ---------------------------------------------------------------------------
// MFMA flash attention over active chunks only. bf16 Q/K/V.
// 4 waves; wave w owns score/output rows w*16..w*16+15 (same C-layout for
// QK^T and PV -> softmax stats stay lane-local: row = l4*4+i).
__global__ __launch_bounds__(256) void attn_kernel(
    const short* __restrict__ qm, const short* __restrict__ km,
    const short* __restrict__ vm, const unsigned long long* __restrict__ keepArr,
    const unsigned int* __restrict__ chunkmask, float* __restrict__ ctx,
    short* __restrict__ ctxbf) {
    __shared__ __align__(16) short Qs[64][72];
    __shared__ __align__(16) short Ks[64][72];
    __shared__ __align__(16) short VT[64][72];   // V transposed: [dim][key]
    __shared__ __align__(16) short Ps[64][72];
    __shared__ unsigned long long keepS[64];
    const int t = threadIdx.x;
    const int lane = t & 63, wave = t >> 6;
    const int l15 = lane & 15, l4 = lane >> 4;
    const int q0 = blockIdx.x << 6;
    const int bh = blockIdx.y;
    const int b = bh / HH, h = bh % HH;

    {   // stage Q (direct bf16 copy)
        int r = t >> 2, seg = t & 3;
        const short* g = qm + ((size_t)bh * SS + q0 + r) * HDIM + seg * 16;
        *(int4*)&Qs[r][seg * 16] = *(const int4*)g;
        *(int4*)&Qs[r][seg * 16 + 8] = *(const int4*)(g + 8);
    }
    unsigned int cm = chunkmask[b * 32 + blockIdx.x];
    float mrun[4], lrun[4];
    v4f oacc[4];
#pragma unroll
    for (int i = 0; i < 4; ++i) { mrun[i] = -1e30f; lrun[i] = 0.f; }
#pragma unroll
    for (int n = 0; n < 4; ++n) oacc[n] = (v4f){0.f, 0.f, 0.f, 0.f};

    while (cm) {
        int kc = __ffs(cm) - 1;
        cm &= cm - 1;
        __syncthreads();   // prev chunk's reads done (1st iter: nothing)
        if (t < 64) keepS[t] = keepArr[((size_t)(b * SS + q0 + t)) * 32 + kc];
        {   // stage K rows + V transposed
            int key = t >> 2, seg = t & 3;
            const short* gk = km + ((size_t)bh * SS + (kc << 6) + key) * HDIM + seg * 16;
            *(int4*)&Ks[key][seg * 16] = *(const int4*)gk;
            *(int4*)&Ks[key][seg * 16 + 8] = *(const int4*)(gk + 8);
            const short* gv = vm + ((size_t)bh * SS + (kc << 6) + key) * HDIM + seg * 16;
            int4 v0 = *(const int4*)gv, v1 = *(const int4*)(gv + 8);
            const short* s0 = (const short*)&v0;
            const short* s1 = (const short*)&v1;
#pragma unroll
            for (int e = 0; e < 8; ++e) VT[seg * 16 + e][key] = s0[e];
#pragma unroll
            for (int e = 0; e < 8; ++e) VT[seg * 16 + 8 + e][key] = s1[e];
        }
        __syncthreads();

        // QK^T: S[64 rows][64 keys], wave computes 16 rows x 64 keys
        v8s qa0 = *(const v8s*)&Qs[wave * 16 + l15][l4 * 8];
        v8s qa1 = *(const v8s*)&Qs[wave * 16 + l15][32 + l4 * 8];
        v4f sacc[4];
#pragma unroll
        for (int n = 0; n < 4; ++n) sacc[n] = (v4f){0.f, 0.f, 0.f, 0.f};
#pragma unroll
        for (int n = 0; n < 4; ++n) {
            v8s kb0 = *(const v8s*)&Ks[n * 16 + l15][l4 * 8];
            v8s kb1 = *(const v8s*)&Ks[n * 16 + l15][32 + l4 * 8];
            sacc[n] = __builtin_amdgcn_mfma_f32_16x16x32_bf16(qa0, kb0, sacc[n], 0, 0, 0);
            sacc[n] = __builtin_amdgcn_mfma_f32_16x16x32_bf16(qa1, kb1, sacc[n], 0, 0, 0);
        }
        // online softmax; row r = wave*16 + l4*4 + i lives in component i
        unsigned long long kp[4];
#pragma unroll
        for (int i = 0; i < 4; ++i) kp[i] = keepS[wave * 16 + l4 * 4 + i];
        float pe[4][4], mloc[4];
#pragma unroll
        for (int i = 0; i < 4; ++i) mloc[i] = -1e30f;
#pragma unroll
        for (int n = 0; n < 4; ++n)
#pragma unroll
            for (int i = 0; i < 4; ++i) {
                bool keep = (kp[i] >> (n * 16 + l15)) & 1;
                float sv = keep ? sacc[n][i] * 0.125f : -1e30f;
                pe[n][i] = sv;
                mloc[i] = fmaxf(mloc[i], sv);
            }
#pragma unroll
        for (int i = 0; i < 4; ++i) {
            mloc[i] = fmaxf(mloc[i], __shfl_xor(mloc[i], 1, 16));
            mloc[i] = fmaxf(mloc[i], __shfl_xor(mloc[i], 2, 16));
            mloc[i] = fmaxf(mloc[i], __shfl_xor(mloc[i], 4, 16));
            mloc[i] = fmaxf(mloc[i], __shfl_xor(mloc[i], 8, 16));
        }
        float psum[4] = {0.f, 0.f, 0.f, 0.f};
#pragma unroll
        for (int n = 0; n < 4; ++n)
#pragma unroll
            for (int i = 0; i < 4; ++i) {
                bool keep = pe[n][i] > -1e29f;
                float mnew = fmaxf(mrun[i], mloc[i]);
                float p = keep ? __expf(pe[n][i] - mnew) : 0.f;
                pe[n][i] = p;
                psum[i] += p;
            }
#pragma unroll
        for (int i = 0; i < 4; ++i) {
            psum[i] += __shfl_xor(psum[i], 1, 16);
            psum[i] += __shfl_xor(psum[i], 2, 16);
            psum[i] += __shfl_xor(psum[i], 4, 16);
            psum[i] += __shfl_xor(psum[i], 8, 16);
            float mnew = fmaxf(mrun[i], mloc[i]);
            float scale = __expf(mrun[i] - mnew);
            lrun[i] = lrun[i] * scale + psum[i];
            mrun[i] = mnew;
#pragma unroll
            for (int n = 0; n < 4; ++n) oacc[n][i] *= scale;
        }
        // P -> bf16 LDS (C-layout write)
#pragma unroll
        for (int n = 0; n < 4; ++n)
#pragma unroll
            for (int i = 0; i < 4; ++i)
                Ps[wave * 16 + l4 * 4 + i][n * 16 + l15] = f2bf(pe[n][i]);
        __syncthreads();

        // PV: out += P[16 rows x 64 keys] * V[64 keys x 64 dims]
        v8s pa0 = *(const v8s*)&Ps[wave * 16 + l15][l4 * 8];
        v8s pa1 = *(const v8s*)&Ps[wave * 16 + l15][32 + l4 * 8];
#pragma unroll
        for (int n = 0; n < 4; ++n) {
            v8s vb0 = *(const v8s*)&VT[n * 16 + l15][l4 * 8];
            v8s vb1 = *(const v8s*)&VT[n * 16 + l15][32 + l4 * 8];
            oacc[n] = __builtin_amdgcn_mfma_f32_16x16x32_bf16(pa0, vb0, oacc[n], 0, 0, 0);
            oacc[n] = __builtin_amdgcn_mfma_f32_16x16x32_bf16(pa1, vb1, oacc[n], 0, 0, 0);
        }
    }
    float invl[4];
#pragma unroll
    for (int i = 0; i < 4; ++i) invl[i] = lrun[i] > 0.f ? 1.f / lrun[i] : 0.f;
#pragma unroll
    for (int n = 0; n < 4; ++n)
#pragma unroll
        for (int i = 0; i < 4; ++i) {
            int r = wave * 16 + l4 * 4 + i;
            size_t off = ((size_t)b * SS + q0 + r) * DD + h * HDIM + n * 16 + l15;
            float val = oacc[n][i] * invl[i];
            ctx[off] = val;
            ctxbf[off] = f2bf(val);
        }
}

// ---------------------------------------------------------------------------
extern "C" void kernel_launch(void* const* d_in, const int* in_sizes, int n_in,
                              void* d_out, int out_size, void* d_ws, size_t ws_size,
                              hipStream_t stream) {
    const float* hs = (const float*)d_in[0];
    const float* tf = (const float*)d_in[1];
    const float* Wq = (const float*)d_in[2];
    const float* Wk = (const float*)d_in[3];
    const float* Wv = (const float*)d_in[4];
    const float* Wo = (const float*)d_in[5];
    const float* bo = (const float*)d_in[6];
    const float* Wg = (const float*)d_in[7];
    const float* bg = (const float*)d_in[8];
    const float* hp = (const float*)d_in[9];
    const float* tb = (const float*)d_in[10];
    const int* msk  = (const int*)d_in[11];
    float* out = (float*)d_out;

    char* w = (char*)d_ws;
    short* qkvbf  = (short*)(w + OFF_QBF);
    float* ctx    = (float*)(w + OFF_CTX);
    short* hsbf   = (short*)(w + OFF_HSBF);
    short* tfbf   = (short*)(w + OFF_TFBF);
    short* ctxbf  = (short*)(w + OFF_CTXBF);
    short* ctx2bf = (short*)(w + OFF_CTX2BF);
    short* wtqkv  = (short*)(w + OFF_WTQKV);
    short* wgT    = (short*)(w + OFF_WGT);
    short* woT    = (short*)(w + OFF_WOT);
    short* hpwT   = (short*)(w + OFF_HPWT);
    float* proj   = (float*)(w + OFF_PROJ);
    unsigned long long* codes = (unsigned long long*)(w + OFF_CODES);
    unsigned long long* keepA = (unsigned long long*)(w + OFF_KEEP);
    unsigned int* cmask = (unsigned int*)(w + OFF_CMASK);

    // 1. fused preprocessing (conv + 3 weight transposes + hpwT)
    prep<<<dim3(5216), 256, 0, stream>>>(
        hs, tf, Wq, Wk, Wv, Wg, Wo, hp,
        hsbf, tfbf, wtqkv, wgT, woT, hpwT);
    // 2. COMBINED QKV + LSH-projection dispatch (mode 3, XCD-swizzled):
    //    bx 0-35: QKV -> bf16 [B,H,S,HD] x3;  bx 36-43: proj -> f32 + bias
    gemm_mfma<2><<<dim3(44, 32), 256, 0, stream>>>(
        hsbf, tfbf, wtqkv, hpwT, tb, proj, qkvbf, 512, 768, 128, 3, 12, nullptr, nullptr);
    // 3-5. codes (+cmask zero), masks, attention
    pack_codes<<<4096, 512, 0, stream>>>(proj, codes, cmask);
    mask_kernel<<<dim3(32, 32, 2), 256, 0, stream>>>(codes, msk, keepA, cmask);
    attn_kernel<<<dim3(32, 24), 256, 0, stream>>>(
        qkvbf, qkvbf + 3145728, qkvbf + 2 * 3145728, keepA, cmask, ctx, ctxbf);
    // 6. gate GEMM + sigmoid-blend epilogue -> ctx2 bf16 (XCD-swizzled)
    gemm_mfma<2><<<dim3(12, 32), 256, 0, stream>>>(
        ctxbf, tfbf, wgT, nullptr, bg, nullptr, ctx2bf, 768, 768, 128, 2, 12, ctx, hs);
    // 7. output projection -> d_out f32 (XCD-swizzled)
    gemm_mfma<2><<<dim3(12, 32), 256, 0, stream>>>(
        ctx2bf, nullptr, woT, nullptr, bo, out, nullptr, 768, 768, 0, 0, 12, nullptr, nullptr);
}

// Round 11
// 117.697 us; speedup vs baseline: 1.1531x; 1.0374x over previous
//
#include <hip/hip_runtime.h>

typedef __attribute__((ext_vector_type(4))) float v4f;
typedef __attribute__((ext_vector_type(8))) short v8s;

// Problem constants
#define BB 2
#define SS 2048
#define DD 768
#define HH 12
#define HDIM 64
#define NWORDS 8          // 512 hash bits = 8 u64
#define HAM_MAX 179       // sim > 0.3  <=>  hamming <= 179

// ws layout (bytes)
#define OFF_QBF    ((size_t)0)             // q,k,v bf16 contiguous 3x6291456
#define OFF_HSBF   ((size_t)31457280)      // 6291456
#define OFF_TFBF   ((size_t)37748736)      // 1048576
#define OFF_CTXBF  ((size_t)38797312)      // 6291456
#define OFF_CTX2BF ((size_t)45088768)      // 6291456
#define OFF_WTQKV  ((size_t)51380224)      // 3538944
#define OFF_WGT    ((size_t)54919168)      // 1376256
#define OFF_WOT    ((size_t)56295424)      // 1179648
#define OFF_HPWT   ((size_t)57475072)      // 917504
#define OFF_CODES  ((size_t)66781184)      // 262144
#define OFF_KEEP   ((size_t)67043328)      // 1048576
#define OFF_CMASK  ((size_t)68091904)      // 256

__device__ inline short f2bf(float x) {
    unsigned u = __float_as_uint(x);
    u = (u + 0x7FFFu + ((u >> 16) & 1u)) >> 16;  // RNE
    return (short)u;
}
__device__ inline float bf2f(short s) {
    return __uint_as_float(((unsigned)(unsigned short)s) << 16);
}

// async global->LDS, 16B per lane, wave-uniform LDS base + lane*16
__device__ __forceinline__ void load_lds16(const void* g, void* l) {
    __builtin_amdgcn_global_load_lds((const __attribute__((address_space(1))) void*)g,
                                     (__attribute__((address_space(3))) void*)l,
                                     16, 0, 0);
}

// ---------------------------------------------------------------------------
// Fused preprocessing: one dispatch, block-range routing.
//   [0,1792)    : conv_act (hs,tf -> bf16); block 0 also zeroes cmask
//   [1792,3520) : tconv3  (Wq/Wk/Wv -> WtQKV transposed bf16)
//   [3520,4192) : tconvW  Wg (896x768 -> wgT)
//   [4192,4768) : tconvW  Wo (768x768 -> woT)
//   [4768,5216) : build_hpwT
__global__ __launch_bounds__(256) void prep(
    const float* __restrict__ hs, const float* __restrict__ tf,
    const float* __restrict__ Wq, const float* __restrict__ Wk,
    const float* __restrict__ Wv, const float* __restrict__ Wg,
    const float* __restrict__ Wo, const float* __restrict__ hp,
    short* __restrict__ hsbf, short* __restrict__ tfbf,
    short* __restrict__ wtqkv, short* __restrict__ wgT,
    short* __restrict__ woT, short* __restrict__ hpwT,
    unsigned int* __restrict__ cmask) {
    __shared__ float T[32][33];
    const int blk = blockIdx.x;
    const int tid = threadIdx.x;
    if (blk < 1792) {
        if (blk == 0 && tid < 64) cmask[tid] = 0u;
        int i = blk * 256 + tid;
        const int na8 = 3145728 / 8;
        const float* src; short* dst; int off;
        if (i < na8) { src = hs; dst = hsbf; off = i << 3; }
        else         { src = tf; dst = tfbf; off = (i - na8) << 3; }
        float4 x = *(const float4*)(src + off);
        float4 y = *(const float4*)(src + off + 4);
        v8s r;
        r[0] = f2bf(x.x); r[1] = f2bf(x.y); r[2] = f2bf(x.z); r[3] = f2bf(x.w);
        r[4] = f2bf(y.x); r[5] = f2bf(y.y); r[6] = f2bf(y.z); r[7] = f2bf(y.w);
        *(v8s*)(dst + off) = r;
        return;
    }
    const int tx = tid & 31, ty = tid >> 5;
    if (blk < 3520) {
        int b = blk - 1792;
        int z = b / 576, rem = b % 576;
        int x = rem % 24, y = rem / 24;
        const float* W = (z == 0) ? Wq : (z == 1) ? Wk : Wv;
        short* Wt = wtqkv + (size_t)z * 589824;
        int n0 = x * 32, k0 = y * 32;
#pragma unroll
        for (int p = 0; p < 4; ++p) {
            int kk = ty + p * 8;
            T[tx][kk] = W[(size_t)(k0 + kk) * 768 + n0 + tx];
        }
        __syncthreads();
#pragma unroll
        for (int p = 0; p < 4; ++p) {
            int nn = ty + p * 8;
            Wt[(size_t)(n0 + nn) * 768 + k0 + tx] = f2bf(T[nn][tx]);
        }
    } else if (blk < 4192) {
        int b = blk - 3520;
        int x = b % 24, y = b / 24;
        int n0 = x * 32, k0 = y * 32;
#pragma unroll
        for (int p = 0; p < 4; ++p) {
            int kk = ty + p * 8;
            T[tx][kk] = Wg[(size_t)(k0 + kk) * 768 + n0 + tx];
        }
        __syncthreads();
#pragma unroll
        for (int p = 0; p < 4; ++p) {
            int nn = ty + p * 8;
            wgT[(size_t)(n0 + nn) * 896 + k0 + tx] = f2bf(T[nn][tx]);
        }
    } else if (blk < 4768) {
        int b = blk - 4192;
        int x = b % 24, y = b / 24;
        int n0 = x * 32, k0 = y * 32;
#pragma unroll
        for (int p = 0; p < 4; ++p) {
            int kk = ty + p * 8;
            T[tx][kk] = Wo[(size_t)(k0 + kk) * 768 + n0 + tx];
        }
        __syncthreads();
#pragma unroll
        for (int p = 0; p < 4; ++p) {
            int nn = ty + p * 8;
            woT[(size_t)(n0 + nn) * 768 + k0 + tx] = f2bf(T[nn][tx]);
        }
    } else {
        int b = blk - 4768;
        int x = b % 28, y = b / 28;
        int kk0 = x * 32, hc0 = y * 32;
        int h = hc0 >> 6, cb = hc0 & 63;
#pragma unroll
        for (int p = 0; p < 4; ++p) {
            int kp = ty + p * 8;
            int gk = kk0 + kp;
            int ks = (gk >= 768) ? gk - 768 : gk;
            float f = hp[((size_t)h * 768 + ks) * 64 + cb + tx];
            T[tx][kp] = (gk >= 768) ? 0.1f * f : f;
        }
        __syncthreads();
#pragma unroll
        for (int p = 0; p < 4; ++p) {
            int cp = ty + p * 8;
            hpwT[(size_t)(hc0 + cp) * 896 + kk0 + tx] = f2bf(T[cp][tx]);
        }
    }
}

// ---------------------------------------------------------------------------
// MFMA bf16 GEMM, 2-phase prefetch double-buffer + XCD swizzle.
// NW = number of B weights sharing one A-stage (QKV fusion: 3x MFMA per
// barrier-pair -> amortizes the m233 stage+barrier overhead).
// BM=128, BN=WN*32, 4 waves (2x2). Linear LDS + global_load_lds(16) + XOR
// source-pre-swizzle (conflict-free, verified r5-r10: SQ_LDS_BANK_CONFLICT=0).
// mode 3 (NW=3, grid 20x32): bx<12 fused QKV (scatter bf16 x3);
//                            bx>=12 proj -> SIGN-PACK direct to codes (u64).
// mode 2 (NW=1): gate blend from bf16 ctx/hs -> bf16 out.
// mode 0 (NW=1): f32 store + bias.
template<int WN, int NW>
__global__ __launch_bounds__(256) void gemm_mfma(
    const short* __restrict__ A, const short* __restrict__ A2,
    const short* __restrict__ Bt, const short* __restrict__ Bt2,
    const float* __restrict__ bias,
    float* __restrict__ outF, short* __restrict__ outB,
    unsigned long long* __restrict__ codesOut,
    int N, int K1, int K2, int mode,
    const short* __restrict__ gctxb, const short* __restrict__ ghsb) {
    constexpr int BN = WN * 32;
    __shared__ __align__(16) short As[2 * 128 * 64];        // 32 KB
    __shared__ __align__(16) short Bs[2 * NW * BN * 64];    // NW*16 KB
    const int t = threadIdx.x;
    const int lane = t & 63, wave = t >> 6;
    const int wm = wave >> 1, wn = wave & 1;
    const int l15 = lane & 15, l4 = lane >> 4;

    // XCD-aware bijective swizzle (gridDim.y==32, total blocks % 8 == 0)
    const int nbx = gridDim.x;
    int flat = blockIdx.x + nbx * blockIdx.y;
    int xcd = flat & 7, j = flat >> 3;
    int by = xcd * 4 + j / nbx;
    int bx = j % nbx;
    const int row0 = by * 128;

    // per-block routing
    int nWact, col0, myMode, Kblk;
    const short* Bp;
    const float* biasp = bias;
    if (mode == 3) {
        if (bx < 12) { nWact = NW; col0 = bx * 64; myMode = 1; Kblk = K1; Bp = Bt; biasp = nullptr; }
        else         { nWact = 1;  col0 = (bx - 12) * 64; myMode = 0; Kblk = K1 + K2; Bp = Bt2; }
    } else {
        nWact = 1; col0 = bx * BN; myMode = mode; Kblk = K1 + K2; Bp = Bt;
    }

    // source swizzle: lane covers row (chunk*8 + lane>>3), 16B slot (lane&7)
    const int lrow = lane >> 3;
    const int scolS = ((lane & 7) ^ lrow) << 3;

    auto STAGE = [&](int buf, int k0) {
        const short* Ap; int ks, strideS;
        if (k0 < K1) { Ap = A;  ks = k0;      strideS = K1; }
        else         { Ap = A2; ks = k0 - K1; strideS = K2; }
#pragma unroll
        for (int qq = 0; qq < 4; ++qq) {
            int c = wave * 4 + qq;                   // A chunk: rows 8c..8c+7
            const short* ga = Ap + (size_t)(row0 + c * 8 + lrow) * strideS + ks + scolS;
            load_lds16(ga, (char*)As + buf * 16384 + c * 1024);
        }
#pragma unroll
        for (int w = 0; w < NW; ++w) {
            if (w < nWact) {
#pragma unroll
                for (int qq = 0; qq < WN; ++qq) {
                    int c = wave * WN + qq;          // B chunk
                    const short* gb = Bp + (size_t)w * 589824 +
                                      (size_t)(col0 + c * 8 + lrow) * Kblk + k0 + scolS;
                    load_lds16(gb, (char*)Bs + (buf * NW + w) * (BN * 128) + c * 1024);
                }
            }
        }
    };

    v4f acc[NW][4][WN];
#pragma unroll
    for (int w = 0; w < NW; ++w)
#pragma unroll
        for (int m = 0; m < 4; ++m)
#pragma unroll
            for (int n = 0; n < WN; ++n) acc[w][m][n] = (v4f){0.f, 0.f, 0.f, 0.f};

    const int nK = Kblk >> 6;
    STAGE(0, 0);
    __syncthreads();
    int cur = 0;
    for (int kt = 0; kt < nK; ++kt) {
        if (kt + 1 < nK) STAGE(cur ^ 1, (kt + 1) << 6);
#pragma unroll
        for (int kk = 0; kk < 2; ++kk) {
            v8s a[4];
#pragma unroll
            for (int m = 0; m < 4; ++m) {
                int row = wm * 64 + m * 16 + l15;
                int byte = (row * 128 + kk * 64 + l4 * 16) ^ ((row & 7) << 4);
                a[m] = *(const v8s*)((const char*)As + cur * 16384 + byte);
            }
#pragma unroll
            for (int w = 0; w < NW; ++w) {
                if (w < nWact) {
                    v8s b[WN];
#pragma unroll
                    for (int n = 0; n < WN; ++n) {
                        int row = wn * (WN * 16) + n * 16 + l15;
                        int byte = (row * 128 + kk * 64 + l4 * 16) ^ ((row & 7) << 4);
                        b[n] = *(const v8s*)((const char*)Bs + (cur * NW + w) * (BN * 128) + byte);
                    }
#pragma unroll
                    for (int m = 0; m < 4; ++m)
#pragma unroll
                        for (int n = 0; n < WN; ++n)
                            acc[w][m][n] = __builtin_amdgcn_mfma_f32_16x16x32_bf16(a[m], b[n], acc[w][m][n], 0, 0, 0);
                }
            }
        }
        __syncthreads();
        cur ^= 1;
    }

    // ---- proj epilogue: sign-pack straight to codes (replaces pack_codes) ----
    if (mode == 3 && myMode == 0) {
        unsigned short* pieces = (unsigned short*)As;  // [128 rows][4 parts], LDS reuse
#pragma unroll
        for (int m = 0; m < 4; ++m)
#pragma unroll
            for (int n = 0; n < WN; ++n) {
                int gc = col0 + (wn * WN + n) * 16 + l15;
                int part = wn * WN + n;
#pragma unroll
                for (int i = 0; i < 4; ++i) {
                    float c = acc[0][m][n][i] + biasp[gc];
                    unsigned long long bal = __ballot(c > 0.f);
                    if (lane < 4) {
                        int rloc = wm * 64 + m * 16 + lane * 4 + i;
                        pieces[rloc * 4 + part] = (unsigned short)(bal >> (lane * 16));
                    }
                }
            }
        __syncthreads();
        if (t < 128) {
            unsigned long long w64 =
                  (unsigned long long)pieces[t * 4 + 0]
                | ((unsigned long long)pieces[t * 4 + 1] << 16)
                | ((unsigned long long)pieces[t * 4 + 2] << 32)
                | ((unsigned long long)pieces[t * 4 + 3] << 48);
            codesOut[(size_t)(row0 + t) * NWORDS + (bx - 12)] = w64;
        }
        return;
    }

#pragma unroll
    for (int m = 0; m < 4; ++m) {
#pragma unroll
        for (int n = 0; n < WN; ++n) {
            int gr0 = row0 + (wm * 4 + m) * 16 + l4 * 4;
            int gc = col0 + (wn * WN + n) * 16 + l15;
#pragma unroll
            for (int i = 0; i < 4; ++i) {
                int gr = gr0 + i;
                if (myMode == 1) {
                    int bb = gr >> 11, s = gr & 2047;
                    int h = gc >> 6, hd = gc & 63;
                    size_t base = (((size_t)(bb * HH + h)) * SS + s) * HDIM + hd;
#pragma unroll
                    for (int w = 0; w < NW; ++w)
                        if (w < nWact)
                            outB[(size_t)w * 3145728 + base] = f2bf(acc[w][m][n][i]);
                } else if (myMode == 0) {
                    float c = acc[0][m][n][i];
                    if (biasp) c += biasp[gc];
                    outF[(size_t)gr * N + gc] = c;
                } else {
                    float c = acc[0][m][n][i] + biasp[gc];
                    float g = 1.f / (1.f + __expf(-c));
                    size_t off = (size_t)gr * N + gc;
                    float cv = bf2f(gctxb[off]);
                    float hv = bf2f(ghsb[off]);
                    outB[off] = f2bf(g * cv + (1.f - g) * hv);
                }
            }
        }
    }
}

// ---------------------------------------------------------------------------
// LSH keep masks: one (qchunk, kchunk, b) tile per block, 2048 blocks.
__global__ __launch_bounds__(256) void mask_kernel(
    const unsigned long long* __restrict__ codes, const int* __restrict__ mask,
    unsigned long long* __restrict__ keepArr, unsigned int* __restrict__ chunkmask) {
    __shared__ unsigned long long ckS[64][NWORDS];
    __shared__ int mskS[64];
    const int t = threadIdx.x;
    const int r = t >> 2, tx = t & 3;
    const int qc = blockIdx.x, kc = blockIdx.y, b = blockIdx.z;
    const int q0 = qc << 6, k0 = kc << 6;

#pragma unroll
    for (int p = 0; p < 2; ++p) {
        int idx = t + (p << 8);
        int jr = idx >> 3, ww = idx & 7;
        ckS[jr][ww ^ (jr >> 4)] =
            codes[((size_t)(b * SS + k0 + jr)) * NWORDS + ww];
    }
    if (t < 64) mskS[t] = mask[b * SS + k0 + t];
    unsigned long long cq[NWORDS];
    {
        const unsigned long long* cp = codes + ((size_t)(b * SS + q0 + r)) * NWORDS;
#pragma unroll
        for (int w = 0; w < NWORDS; ++w) cq[w] = cp[w];
    }
    __syncthreads();

    unsigned long long k64 = 0;
#pragma unroll
    for (int j16 = 0; j16 < 16; ++j16) {
        int j = (tx << 4) + j16;
        int ham = 0;
#pragma unroll
        for (int w = 0; w < NWORDS; ++w)
            ham += __popcll(cq[w] ^ ckS[j][w ^ tx]);
        if (ham <= HAM_MAX && mskS[j]) k64 |= 1ull << j;
    }
    k64 |= __shfl_xor(k64, 1, 4);
    k64 |= __shfl_xor(k64, 2, 4);
    if (tx == 0) keepArr[((size_t)(b * SS + q0 + r)) * 32 + kc] = k64;
    if (__syncthreads_or(k64 != 0) && t == 0)
        atomicOr(&chunkmask[b * 32 + qc], 1u << kc);
}

// ---------------------------------------------------------------------------
// MFMA flash attention over active chunks only. bf16 Q/K/V -> bf16 ctx.
__global__ __launch_bounds__(256) void attn_kernel(
    const short* __restrict__ qm, const short* __restrict__ km,
    const short* __restrict__ vm, const unsigned long long* __restrict__ keepArr,
    const unsigned int* __restrict__ chunkmask, short* __restrict__ ctxbf) {
    __shared__ __align__(16) short Qs[64][72];
    __shared__ __align__(16) short Ks[64][72];
    __shared__ __align__(16) short VT[64][72];   // V transposed: [dim][key]
    __shared__ __align__(16) short Ps[64][72];
    __shared__ unsigned long long keepS[64];
    const int t = threadIdx.x;
    const int lane = t & 63, wave = t >> 6;
    const int l15 = lane & 15, l4 = lane >> 4;
    const int q0 = blockIdx.x << 6;
    const int bh = blockIdx.y;
    const int b = bh / HH, h = bh % HH;

    {   // stage Q
        int r = t >> 2, seg = t & 3;
        const short* g = qm + ((size_t)bh * SS + q0 + r) * HDIM + seg * 16;
        *(int4*)&Qs[r][seg * 16] = *(const int4*)g;
        *(int4*)&Qs[r][seg * 16 + 8] = *(const int4*)(g + 8);
    }
    unsigned int cm = chunkmask[b * 32 + blockIdx.x];
    float mrun[4], lrun[4];
    v4f oacc[4];
#pragma unroll
    for (int i = 0; i < 4; ++i) { mrun[i] = -1e30f; lrun[i] = 0.f; }
#pragma unroll
    for (int n = 0; n < 4; ++n) oacc[n] = (v4f){0.f, 0.f, 0.f, 0.f};

    while (cm) {
        int kc = __ffs(cm) - 1;
        cm &= cm - 1;
        __syncthreads();
        if (t < 64) keepS[t] = keepArr[((size_t)(b * SS + q0 + t)) * 32 + kc];
        {   // stage K rows + V transposed
            int key = t >> 2, seg = t & 3;
            const short* gk = km + ((size_t)bh * SS + (kc << 6) + key) * HDIM + seg * 16;
            *(int4*)&Ks[key][seg * 16] = *(const int4*)gk;
            *(int4*)&Ks[key][seg * 16 + 8] = *(const int4*)(gk + 8);
            const short* gv = vm + ((size_t)bh * SS + (kc << 6) + key) * HDIM + seg * 16;
            int4 v0 = *(const int4*)gv, v1 = *(const int4*)(gv + 8);
            const short* s0 = (const short*)&v0;
            const short* s1 = (const short*)&v1;
#pragma unroll
            for (int e = 0; e < 8; ++e) VT[seg * 16 + e][key] = s0[e];
#pragma unroll
            for (int e = 0; e < 8; ++e) VT[seg * 16 + 8 + e][key] = s1[e];
        }
        __syncthreads();

        v8s qa0 = *(const v8s*)&Qs[wave * 16 + l15][l4 * 8];
        v8s qa1 = *(const v8s*)&Qs[wave * 16 + l15][32 + l4 * 8];
        v4f sacc[4];
#pragma unroll
        for (int n = 0; n < 4; ++n) sacc[n] = (v4f){0.f, 0.f, 0.f, 0.f};
#pragma unroll
        for (int n = 0; n < 4; ++n) {
            v8s kb0 = *(const v8s*)&Ks[n * 16 + l15][l4 * 8];
            v8s kb1 = *(const v8s*)&Ks[n * 16 + l15][32 + l4 * 8];
            sacc[n] = __builtin_amdgcn_mfma_f32_16x16x32_bf16(qa0, kb0, sacc[n], 0, 0, 0);
            sacc[n] = __builtin_amdgcn_mfma_f32_16x16x32_bf16(qa1, kb1, sacc[n], 0, 0, 0);
        }
        unsigned long long kp[4];
#pragma unroll
        for (int i = 0; i < 4; ++i) kp[i] = keepS[wave * 16 + l4 * 4 + i];
        float pe[4][4], mloc[4];
#pragma unroll
        for (int i = 0; i < 4; ++i) mloc[i] = -1e30f;
#pragma unroll
        for (int n = 0; n < 4; ++n)
#pragma unroll
            for (int i = 0; i < 4; ++i) {
                bool keep = (kp[i] >> (n * 16 + l15)) & 1;
                float sv = keep ? sacc[n][i] * 0.125f : -1e30f;
                pe[n][i] = sv;
                mloc[i] = fmaxf(mloc[i], sv);
            }
#pragma unroll
        for (int i = 0; i < 4; ++i) {
            mloc[i] = fmaxf(mloc[i], __shfl_xor(mloc[i], 1, 16));
            mloc[i] = fmaxf(mloc[i], __shfl_xor(mloc[i], 2, 16));
            mloc[i] = fmaxf(mloc[i], __shfl_xor(mloc[i], 4, 16));
            mloc[i] = fmaxf(mloc[i], __shfl_xor(mloc[i], 8, 16));
        }
        float psum[4] = {0.f, 0.f, 0.f, 0.f};
#pragma unroll
        for (int n = 0; n < 4; ++n)
#pragma unroll
            for (int i = 0; i < 4; ++i) {
                bool keep = pe[n][i] > -1e29f;
                float mnew = fmaxf(mrun[i], mloc[i]);
                float p = keep ? __expf(pe[n][i] - mnew) : 0.f;
                pe[n][i] = p;
                psum[i] += p;
            }
#pragma unroll
        for (int i = 0; i < 4; ++i) {
            psum[i] += __shfl_xor(psum[i], 1, 16);
            psum[i] += __shfl_xor(psum[i], 2, 16);
            psum[i] += __shfl_xor(psum[i], 4, 16);
            psum[i] += __shfl_xor(psum[i], 8, 16);
            float mnew = fmaxf(mrun[i], mloc[i]);
            float scale = __expf(mrun[i] - mnew);
            lrun[i] = lrun[i] * scale + psum[i];
            mrun[i] = mnew;
#pragma unroll
            for (int n = 0; n < 4; ++n) oacc[n][i] *= scale;
        }
#pragma unroll
        for (int n = 0; n < 4; ++n)
#pragma unroll
            for (int i = 0; i < 4; ++i)
                Ps[wave * 16 + l4 * 4 + i][n * 16 + l15] = f2bf(pe[n][i]);
        __syncthreads();

        v8s pa0 = *(const v8s*)&Ps[wave * 16 + l15][l4 * 8];
        v8s pa1 = *(const v8s*)&Ps[wave * 16 + l15][32 + l4 * 8];
#pragma unroll
        for (int n = 0; n < 4; ++n) {
            v8s vb0 = *(const v8s*)&VT[n * 16 + l15][l4 * 8];
            v8s vb1 = *(const v8s*)&VT[n * 16 + l15][32 + l4 * 8];
            oacc[n] = __builtin_amdgcn_mfma_f32_16x16x32_bf16(pa0, vb0, oacc[n], 0, 0, 0);
            oacc[n] = __builtin_amdgcn_mfma_f32_16x16x32_bf16(pa1, vb1, oacc[n], 0, 0, 0);
        }
    }
    float invl[4];
#pragma unroll
    for (int i = 0; i < 4; ++i) invl[i] = lrun[i] > 0.f ? 1.f / lrun[i] : 0.f;
#pragma unroll
    for (int n = 0; n < 4; ++n)
#pragma unroll
        for (int i = 0; i < 4; ++i) {
            int r = wave * 16 + l4 * 4 + i;
            size_t off = ((size_t)b * SS + q0 + r) * DD + h * HDIM + n * 16 + l15;
            ctxbf[off] = f2bf(oacc[n][i] * invl[i]);
        }
}

// ---------------------------------------------------------------------------
extern "C" void kernel_launch(void* const* d_in, const int* in_sizes, int n_in,
                              void* d_out, int out_size, void* d_ws, size_t ws_size,
                              hipStream_t stream) {
    const float* hs = (const float*)d_in[0];
    const float* tf = (const float*)d_in[1];
    const float* Wq = (const float*)d_in[2];
    const float* Wk = (const float*)d_in[3];
    const float* Wv = (const float*)d_in[4];
    const float* Wo = (const float*)d_in[5];
    const float* bo = (const float*)d_in[6];
    const float* Wg = (const float*)d_in[7];
    const float* bg = (const float*)d_in[8];
    const float* hp = (const float*)d_in[9];
    const float* tb = (const float*)d_in[10];
    const int* msk  = (const int*)d_in[11];
    float* out = (float*)d_out;

    char* w = (char*)d_ws;
    short* qkvbf  = (short*)(w + OFF_QBF);
    short* hsbf   = (short*)(w + OFF_HSBF);
    short* tfbf   = (short*)(w + OFF_TFBF);
    short* ctxbf  = (short*)(w + OFF_CTXBF);
    short* ctx2bf = (short*)(w + OFF_CTX2BF);
    short* wtqkv  = (short*)(w + OFF_WTQKV);
    short* wgT    = (short*)(w + OFF_WGT);
    short* woT    = (short*)(w + OFF_WOT);
    short* hpwT   = (short*)(w + OFF_HPWT);
    unsigned long long* codes = (unsigned long long*)(w + OFF_CODES);
    unsigned long long* keepA = (unsigned long long*)(w + OFF_KEEP);
    unsigned int* cmask = (unsigned int*)(w + OFF_CMASK);

    // 1. fused preprocessing (conv + weight transposes + hpwT + cmask zero)
    prep<<<dim3(5216), 256, 0, stream>>>(
        hs, tf, Wq, Wk, Wv, Wg, Wo, hp,
        hsbf, tfbf, wtqkv, wgT, woT, hpwT, cmask);
    // 2. FUSED QKV(3-weights-per-block) + proj-with-sign-pack (mode 3):
    //    bx 0-11: QKV -> bf16 [B,H,S,HD] x3;  bx 12-19: proj -> codes u64
    gemm_mfma<2, 3><<<dim3(20, 32), 256, 0, stream>>>(
        hsbf, tfbf, wtqkv, hpwT, tb, nullptr, qkvbf, codes,
        512, 768, 128, 3, nullptr, nullptr);
    // 3-4. masks, attention
    mask_kernel<<<dim3(32, 32, 2), 256, 0, stream>>>(codes, msk, keepA, cmask);
    attn_kernel<<<dim3(32, 24), 256, 0, stream>>>(
        qkvbf, qkvbf + 3145728, qkvbf + 2 * 3145728, keepA, cmask, ctxbf);
    // 5. gate GEMM + sigmoid-blend (bf16 inputs) -> ctx2 bf16
    gemm_mfma<2, 1><<<dim3(12, 32), 256, 0, stream>>>(
        ctxbf, tfbf, wgT, nullptr, bg, nullptr, ctx2bf, nullptr,
        768, 768, 128, 2, ctxbf, hsbf);
    // 6. output projection -> d_out f32
    gemm_mfma<2, 1><<<dim3(12, 32), 256, 0, stream>>>(
        ctx2bf, nullptr, woT, nullptr, bo, out, nullptr, nullptr,
        768, 768, 0, 0, nullptr, nullptr);
}

// Round 12
// 104.012 us; speedup vs baseline: 1.3048x; 1.1316x over previous
//
#include <hip/hip_runtime.h>

typedef __attribute__((ext_vector_type(4))) float v4f;
typedef __attribute__((ext_vector_type(8))) short v8s;

// Problem constants
#define BB 2
#define SS 2048
#define DD 768
#define HH 12
#define HDIM 64
#define NWORDS 8          // 512 hash bits = 8 u64
#define HAM_MAX 179       // sim > 0.3  <=>  hamming <= 179

// ws layout (bytes)
#define OFF_QBF    ((size_t)0)             // q,k,v bf16 contiguous 3x6291456
#define OFF_HSBF   ((size_t)31457280)      // 6291456
#define OFF_TFBF   ((size_t)37748736)      // 1048576
#define OFF_CTXBF  ((size_t)38797312)      // 6291456
#define OFF_CTX2BF ((size_t)45088768)      // 6291456
#define OFF_WTQKV  ((size_t)51380224)      // 3538944
#define OFF_WGT    ((size_t)54919168)      // 1376256
#define OFF_WOT    ((size_t)56295424)      // 1179648
#define OFF_HPWT   ((size_t)57475072)      // 917504
#define OFF_CODES  ((size_t)66781184)      // 262144
#define OFF_KEEP   ((size_t)67043328)      // 1048576
#define OFF_CMASK  ((size_t)68091904)      // 256

__device__ inline short f2bf(float x) {
    unsigned u = __float_as_uint(x);
    u = (u + 0x7FFFu + ((u >> 16) & 1u)) >> 16;  // RNE
    return (short)u;
}
__device__ inline float bf2f(short s) {
    return __uint_as_float(((unsigned)(unsigned short)s) << 16);
}

// async global->LDS, 16B per lane, wave-uniform LDS base + lane*16
__device__ __forceinline__ void load_lds16(const void* g, void* l) {
    __builtin_amdgcn_global_load_lds((const __attribute__((address_space(1))) void*)g,
                                     (__attribute__((address_space(3))) void*)l,
                                     16, 0, 0);
}

// ---------------------------------------------------------------------------
// Fused preprocessing: one dispatch, block-range routing.
//   [0,1792)    : conv_act (hs,tf -> bf16); block 0 also zeroes cmask
//   [1792,3520) : tconv3  (Wq/Wk/Wv -> WtQKV transposed bf16)
//   [3520,4192) : tconvW  Wg (896x768 -> wgT)
//   [4192,4768) : tconvW  Wo (768x768 -> woT)
//   [4768,5216) : build_hpwT
__global__ __launch_bounds__(256) void prep(
    const float* __restrict__ hs, const float* __restrict__ tf,
    const float* __restrict__ Wq, const float* __restrict__ Wk,
    const float* __restrict__ Wv, const float* __restrict__ Wg,
    const float* __restrict__ Wo, const float* __restrict__ hp,
    short* __restrict__ hsbf, short* __restrict__ tfbf,
    short* __restrict__ wtqkv, short* __restrict__ wgT,
    short* __restrict__ woT, short* __restrict__ hpwT,
    unsigned int* __restrict__ cmask) {
    __shared__ float T[32][33];
    const int blk = blockIdx.x;
    const int tid = threadIdx.x;
    if (blk < 1792) {
        if (blk == 0 && tid < 64) cmask[tid] = 0u;
        int i = blk * 256 + tid;
        const int na8 = 3145728 / 8;
        const float* src; short* dst; int off;
        if (i < na8) { src = hs; dst = hsbf; off = i << 3; }
        else         { src = tf; dst = tfbf; off = (i - na8) << 3; }
        float4 x = *(const float4*)(src + off);
        float4 y = *(const float4*)(src + off + 4);
        v8s r;
        r[0] = f2bf(x.x); r[1] = f2bf(x.y); r[2] = f2bf(x.z); r[3] = f2bf(x.w);
        r[4] = f2bf(y.x); r[5] = f2bf(y.y); r[6] = f2bf(y.z); r[7] = f2bf(y.w);
        *(v8s*)(dst + off) = r;
        return;
    }
    const int tx = tid & 31, ty = tid >> 5;
    if (blk < 3520) {
        int b = blk - 1792;
        int z = b / 576, rem = b % 576;
        int x = rem % 24, y = rem / 24;
        const float* W = (z == 0) ? Wq : (z == 1) ? Wk : Wv;
        short* Wt = wtqkv + (size_t)z * 589824;
        int n0 = x * 32, k0 = y * 32;
#pragma unroll
        for (int p = 0; p < 4; ++p) {
            int kk = ty + p * 8;
            T[tx][kk] = W[(size_t)(k0 + kk) * 768 + n0 + tx];
        }
        __syncthreads();
#pragma unroll
        for (int p = 0; p < 4; ++p) {
            int nn = ty + p * 8;
            Wt[(size_t)(n0 + nn) * 768 + k0 + tx] = f2bf(T[nn][tx]);
        }
    } else if (blk < 4192) {
        int b = blk - 3520;
        int x = b % 24, y = b / 24;
        int n0 = x * 32, k0 = y * 32;
#pragma unroll
        for (int p = 0; p < 4; ++p) {
            int kk = ty + p * 8;
            T[tx][kk] = Wg[(size_t)(k0 + kk) * 768 + n0 + tx];
        }
        __syncthreads();
#pragma unroll
        for (int p = 0; p < 4; ++p) {
            int nn = ty + p * 8;
            wgT[(size_t)(n0 + nn) * 896 + k0 + tx] = f2bf(T[nn][tx]);
        }
    } else if (blk < 4768) {
        int b = blk - 4192;
        int x = b % 24, y = b / 24;
        int n0 = x * 32, k0 = y * 32;
#pragma unroll
        for (int p = 0; p < 4; ++p) {
            int kk = ty + p * 8;
            T[tx][kk] = Wo[(size_t)(k0 + kk) * 768 + n0 + tx];
        }
        __syncthreads();
#pragma unroll
        for (int p = 0; p < 4; ++p) {
            int nn = ty + p * 8;
            woT[(size_t)(n0 + nn) * 768 + k0 + tx] = f2bf(T[nn][tx]);
        }
    } else {
        int b = blk - 4768;
        int x = b % 28, y = b / 28;
        int kk0 = x * 32, hc0 = y * 32;
        int h = hc0 >> 6, cb = hc0 & 63;
#pragma unroll
        for (int p = 0; p < 4; ++p) {
            int kp = ty + p * 8;
            int gk = kk0 + kp;
            int ks = (gk >= 768) ? gk - 768 : gk;
            float f = hp[((size_t)h * 768 + ks) * 64 + cb + tx];
            T[tx][kp] = (gk >= 768) ? 0.1f * f : f;
        }
        __syncthreads();
#pragma unroll
        for (int p = 0; p < 4; ++p) {
            int cp = ty + p * 8;
            hpwT[(size_t)(hc0 + cp) * 896 + kk0 + tx] = f2bf(T[cp][tx]);
        }
    }
}

// ---------------------------------------------------------------------------
// MFMA bf16 GEMM, 2-phase prefetch double-buffer + XCD swizzle.
// NW = B-slots sharing one A-stage. mode 3 grid is EXACTLY 512 blocks
// (16x32) = 2 blocks/CU x 256 CUs -> single occupancy round, no tail:
//   bx<12 : fused QKV (3 weights, nWact=3), K=768, scatter bf16 x3
//   bx>=12: proj BN=128 (two 64-col halves in slots w=0,1, nWact=2),
//           K=896 (A2 path), sign-pack epilogue -> 2 code words/block.
// mode 2 (NW=1): gate blend from bf16 ctx/hs -> bf16 out.
// mode 0 (NW=1): f32 store + bias.
// Linear LDS + global_load_lds(16) + XOR source-pre-swizzle (conflict-free,
// verified r5-r11: SQ_LDS_BANK_CONFLICT == 0).
template<int WN, int NW>
__global__ __launch_bounds__(256) void gemm_mfma(
    const short* __restrict__ A, const short* __restrict__ A2,
    const short* __restrict__ Bt, const short* __restrict__ Bt2,
    const float* __restrict__ bias,
    float* __restrict__ outF, short* __restrict__ outB,
    unsigned long long* __restrict__ codesOut,
    int N, int K1, int K2, int mode,
    const short* __restrict__ gctxb, const short* __restrict__ ghsb) {
    constexpr int BN = WN * 32;
    __shared__ __align__(16) short As[2 * 128 * 64];        // 32 KB
    __shared__ __align__(16) short Bs[2 * NW * BN * 64];    // NW*16 KB
    const int t = threadIdx.x;
    const int lane = t & 63, wave = t >> 6;
    const int wm = wave >> 1, wn = wave & 1;
    const int l15 = lane & 15, l4 = lane >> 4;

    // XCD-aware bijective swizzle (gridDim.y==32, total blocks % 8 == 0)
    const int nbx = gridDim.x;
    int flat = blockIdx.x + nbx * blockIdx.y;
    int xcd = flat & 7, j = flat >> 3;
    int by = xcd * 4 + j / nbx;
    int bx = j % nbx;
    const int row0 = by * 128;

    // per-block routing
    int nWact, col0, myMode, Kblk;
    const short* Bp;
    const float* biasp = bias;
    if (mode == 3) {
        if (bx < 12) { nWact = NW; col0 = bx * 64;        myMode = 1; Kblk = K1;      Bp = Bt;  biasp = nullptr; }
        else         { nWact = 2;  col0 = (bx - 12) * 128; myMode = 0; Kblk = K1 + K2; Bp = Bt2; }
    } else {
        nWact = 1; col0 = bx * BN; myMode = mode; Kblk = K1 + K2; Bp = Bt;
    }
    // B-slot addressing: QKV -> separate weight matrices (stride 589824);
    // proj/gate/out -> column-half offset w*64 rows within one matrix.
    const bool sepW = (myMode == 1);

    // source swizzle: lane covers row (chunk*8 + lane>>3), 16B slot (lane&7)
    const int lrow = lane >> 3;
    const int scolS = ((lane & 7) ^ lrow) << 3;

    auto STAGE = [&](int buf, int k0) {
        const short* Ap; int ks, strideS;
        if (k0 < K1) { Ap = A;  ks = k0;      strideS = K1; }
        else         { Ap = A2; ks = k0 - K1; strideS = K2; }
#pragma unroll
        for (int qq = 0; qq < 4; ++qq) {
            int c = wave * 4 + qq;                   // A chunk: rows 8c..8c+7
            const short* ga = Ap + (size_t)(row0 + c * 8 + lrow) * strideS + ks + scolS;
            load_lds16(ga, (char*)As + buf * 16384 + c * 1024);
        }
#pragma unroll
        for (int w = 0; w < NW; ++w) {
            if (w < nWact) {
#pragma unroll
                for (int qq = 0; qq < WN; ++qq) {
                    int c = wave * WN + qq;          // B chunk
                    size_t rowIdx = (size_t)(col0 + (sepW ? 0 : w * 64) + c * 8 + lrow);
                    const short* gb = Bp + (sepW ? (size_t)w * 589824 : (size_t)0) +
                                      rowIdx * Kblk + k0 + scolS;
                    load_lds16(gb, (char*)Bs + (buf * NW + w) * (BN * 128) + c * 1024);
                }
            }
        }
    };

    v4f acc[NW][4][WN];
#pragma unroll
    for (int w = 0; w < NW; ++w)
#pragma unroll
        for (int m = 0; m < 4; ++m)
#pragma unroll
            for (int n = 0; n < WN; ++n) acc[w][m][n] = (v4f){0.f, 0.f, 0.f, 0.f};

    const int nK = Kblk >> 6;
    STAGE(0, 0);
    __syncthreads();
    int cur = 0;
    for (int kt = 0; kt < nK; ++kt) {
        if (kt + 1 < nK) STAGE(cur ^ 1, (kt + 1) << 6);
#pragma unroll
        for (int kk = 0; kk < 2; ++kk) {
            v8s a[4];
#pragma unroll
            for (int m = 0; m < 4; ++m) {
                int row = wm * 64 + m * 16 + l15;
                int byte = (row * 128 + kk * 64 + l4 * 16) ^ ((row & 7) << 4);
                a[m] = *(const v8s*)((const char*)As + cur * 16384 + byte);
            }
#pragma unroll
            for (int w = 0; w < NW; ++w) {
                if (w < nWact) {
                    v8s b[WN];
#pragma unroll
                    for (int n = 0; n < WN; ++n) {
                        int row = wn * (WN * 16) + n * 16 + l15;
                        int byte = (row * 128 + kk * 64 + l4 * 16) ^ ((row & 7) << 4);
                        b[n] = *(const v8s*)((const char*)Bs + (cur * NW + w) * (BN * 128) + byte);
                    }
#pragma unroll
                    for (int m = 0; m < 4; ++m)
#pragma unroll
                        for (int n = 0; n < WN; ++n)
                            acc[w][m][n] = __builtin_amdgcn_mfma_f32_16x16x32_bf16(a[m], b[n], acc[w][m][n], 0, 0, 0);
                }
            }
        }
        __syncthreads();
        cur ^= 1;
    }

    // ---- proj epilogue: sign-pack 2 code words straight to codes ----
    if (mode == 3 && myMode == 0) {
        unsigned short* pieces = (unsigned short*)As;  // [128 rows][8 parts]
#pragma unroll
        for (int w = 0; w < 2; ++w)
#pragma unroll
            for (int m = 0; m < 4; ++m)
#pragma unroll
                for (int n = 0; n < WN; ++n) {
                    int gc = col0 + w * 64 + (wn * WN + n) * 16 + l15;
                    int part = w * 4 + wn * WN + n;
#pragma unroll
                    for (int i = 0; i < 4; ++i) {
                        float c = acc[w][m][n][i] + biasp[gc];
                        unsigned long long bal = __ballot(c > 0.f);
                        if (lane < 4) {
                            int rloc = wm * 64 + m * 16 + lane * 4 + i;
                            pieces[rloc * 8 + part] = (unsigned short)(bal >> (lane * 16));
                        }
                    }
                }
        __syncthreads();
        if (t < 256) {
            int row = t >> 1, word = t & 1;
            const unsigned short* pp = pieces + row * 8 + word * 4;
            unsigned long long w64 = (unsigned long long)pp[0]
                | ((unsigned long long)pp[1] << 16)
                | ((unsigned long long)pp[2] << 32)
                | ((unsigned long long)pp[3] << 48);
            codesOut[(size_t)(row0 + row) * NWORDS + ((col0 >> 6) + word)] = w64;
        }
        return;
    }

#pragma unroll
    for (int m = 0; m < 4; ++m) {
#pragma unroll
        for (int n = 0; n < WN; ++n) {
            int gr0 = row0 + (wm * 4 + m) * 16 + l4 * 4;
            int gc = col0 + (wn * WN + n) * 16 + l15;
#pragma unroll
            for (int i = 0; i < 4; ++i) {
                int gr = gr0 + i;
                if (myMode == 1) {
                    int bb = gr >> 11, s = gr & 2047;
                    int h = gc >> 6, hd = gc & 63;
                    size_t base = (((size_t)(bb * HH + h)) * SS + s) * HDIM + hd;
#pragma unroll
                    for (int w = 0; w < NW; ++w)
                        if (w < nWact)
                            outB[(size_t)w * 3145728 + base] = f2bf(acc[w][m][n][i]);
                } else if (myMode == 0) {
                    float c = acc[0][m][n][i];
                    if (biasp) c += biasp[gc];
                    outF[(size_t)gr * N + gc] = c;
                } else {
                    float c = acc[0][m][n][i] + biasp[gc];
                    float g = 1.f / (1.f + __expf(-c));
                    size_t off = (size_t)gr * N + gc;
                    float cv = bf2f(gctxb[off]);
                    float hv = bf2f(ghsb[off]);
                    outB[off] = f2bf(g * cv + (1.f - g) * hv);
                }
            }
        }
    }
}

// ---------------------------------------------------------------------------
// LSH keep masks: one (qchunk, kchunk, b) tile per block, 2048 blocks.
__global__ __launch_bounds__(256) void mask_kernel(
    const unsigned long long* __restrict__ codes, const int* __restrict__ mask,
    unsigned long long* __restrict__ keepArr, unsigned int* __restrict__ chunkmask) {
    __shared__ unsigned long long ckS[64][NWORDS];
    __shared__ int mskS[64];
    const int t = threadIdx.x;
    const int r = t >> 2, tx = t & 3;
    const int qc = blockIdx.x, kc = blockIdx.y, b = blockIdx.z;
    const int q0 = qc << 6, k0 = kc << 6;

#pragma unroll
    for (int p = 0; p < 2; ++p) {
        int idx = t + (p << 8);
        int jr = idx >> 3, ww = idx & 7;
        ckS[jr][ww ^ (jr >> 4)] =
            codes[((size_t)(b * SS + k0 + jr)) * NWORDS + ww];
    }
    if (t < 64) mskS[t] = mask[b * SS + k0 + t];
    unsigned long long cq[NWORDS];
    {
        const unsigned long long* cp = codes + ((size_t)(b * SS + q0 + r)) * NWORDS;
#pragma unroll
        for (int w = 0; w < NWORDS; ++w) cq[w] = cp[w];
    }
    __syncthreads();

    unsigned long long k64 = 0;
#pragma unroll
    for (int j16 = 0; j16 < 16; ++j16) {
        int j = (tx << 4) + j16;
        int ham = 0;
#pragma unroll
        for (int w = 0; w < NWORDS; ++w)
            ham += __popcll(cq[w] ^ ckS[j][w ^ tx]);
        if (ham <= HAM_MAX && mskS[j]) k64 |= 1ull << j;
    }
    k64 |= __shfl_xor(k64, 1, 4);
    k64 |= __shfl_xor(k64, 2, 4);
    if (tx == 0) keepArr[((size_t)(b * SS + q0 + r)) * 32 + kc] = k64;
    if (__syncthreads_or(k64 != 0) && t == 0)
        atomicOr(&chunkmask[b * 32 + qc], 1u << kc);
}

// ---------------------------------------------------------------------------
// MFMA flash attention over active chunks only. bf16 Q/K/V -> bf16 ctx.
__global__ __launch_bounds__(256) void attn_kernel(
    const short* __restrict__ qm, const short* __restrict__ km,
    const short* __restrict__ vm, const unsigned long long* __restrict__ keepArr,
    const unsigned int* __restrict__ chunkmask, short* __restrict__ ctxbf) {
    __shared__ __align__(16) short Qs[64][72];
    __shared__ __align__(16) short Ks[64][72];
    __shared__ __align__(16) short VT[64][72];   // V transposed: [dim][key]
    __shared__ __align__(16) short Ps[64][72];
    __shared__ unsigned long long keepS[64];
    const int t = threadIdx.x;
    const int lane = t & 63, wave = t >> 6;
    const int l15 = lane & 15, l4 = lane >> 4;
    const int q0 = blockIdx.x << 6;
    const int bh = blockIdx.y;
    const int b = bh / HH, h = bh % HH;

    {   // stage Q
        int r = t >> 2, seg = t & 3;
        const short* g = qm + ((size_t)bh * SS + q0 + r) * HDIM + seg * 16;
        *(int4*)&Qs[r][seg * 16] = *(const int4*)g;
        *(int4*)&Qs[r][seg * 16 + 8] = *(const int4*)(g + 8);
    }
    unsigned int cm = chunkmask[b * 32 + blockIdx.x];
    float mrun[4], lrun[4];
    v4f oacc[4];
#pragma unroll
    for (int i = 0; i < 4; ++i) { mrun[i] = -1e30f; lrun[i] = 0.f; }
#pragma unroll
    for (int n = 0; n < 4; ++n) oacc[n] = (v4f){0.f, 0.f, 0.f, 0.f};

    while (cm) {
        int kc = __ffs(cm) - 1;
        cm &= cm - 1;
        __syncthreads();
        if (t < 64) keepS[t] = keepArr[((size_t)(b * SS + q0 + t)) * 32 + kc];
        {   // stage K rows + V transposed
            int key = t >> 2, seg = t & 3;
            const short* gk = km + ((size_t)bh * SS + (kc << 6) + key) * HDIM + seg * 16;
            *(int4*)&Ks[key][seg * 16] = *(const int4*)gk;
            *(int4*)&Ks[key][seg * 16 + 8] = *(const int4*)(gk + 8);
            const short* gv = vm + ((size_t)bh * SS + (kc << 6) + key) * HDIM + seg * 16;
            int4 v0 = *(const int4*)gv, v1 = *(const int4*)(gv + 8);
            const short* s0 = (const short*)&v0;
            const short* s1 = (const short*)&v1;
#pragma unroll
            for (int e = 0; e < 8; ++e) VT[seg * 16 + e][key] = s0[e];
#pragma unroll
            for (int e = 0; e < 8; ++e) VT[seg * 16 + 8 + e][key] = s1[e];
        }
        __syncthreads();

        v8s qa0 = *(const v8s*)&Qs[wave * 16 + l15][l4 * 8];
        v8s qa1 = *(const v8s*)&Qs[wave * 16 + l15][32 + l4 * 8];
        v4f sacc[4];
#pragma unroll
        for (int n = 0; n < 4; ++n) sacc[n] = (v4f){0.f, 0.f, 0.f, 0.f};
#pragma unroll
        for (int n = 0; n < 4; ++n) {
            v8s kb0 = *(const v8s*)&Ks[n * 16 + l15][l4 * 8];
            v8s kb1 = *(const v8s*)&Ks[n * 16 + l15][32 + l4 * 8];
            sacc[n] = __builtin_amdgcn_mfma_f32_16x16x32_bf16(qa0, kb0, sacc[n], 0, 0, 0);
            sacc[n] = __builtin_amdgcn_mfma_f32_16x16x32_bf16(qa1, kb1, sacc[n], 0, 0, 0);
        }
        unsigned long long kp[4];
#pragma unroll
        for (int i = 0; i < 4; ++i) kp[i] = keepS[wave * 16 + l4 * 4 + i];
        float pe[4][4], mloc[4];
#pragma unroll
        for (int i = 0; i < 4; ++i) mloc[i] = -1e30f;
#pragma unroll
        for (int n = 0; n < 4; ++n)
#pragma unroll
            for (int i = 0; i < 4; ++i) {
                bool keep = (kp[i] >> (n * 16 + l15)) & 1;
                float sv = keep ? sacc[n][i] * 0.125f : -1e30f;
                pe[n][i] = sv;
                mloc[i] = fmaxf(mloc[i], sv);
            }
#pragma unroll
        for (int i = 0; i < 4; ++i) {
            mloc[i] = fmaxf(mloc[i], __shfl_xor(mloc[i], 1, 16));
            mloc[i] = fmaxf(mloc[i], __shfl_xor(mloc[i], 2, 16));
            mloc[i] = fmaxf(mloc[i], __shfl_xor(mloc[i], 4, 16));
            mloc[i] = fmaxf(mloc[i], __shfl_xor(mloc[i], 8, 16));
        }
        float psum[4] = {0.f, 0.f, 0.f, 0.f};
#pragma unroll
        for (int n = 0; n < 4; ++n)
#pragma unroll
            for (int i = 0; i < 4; ++i) {
                bool keep = pe[n][i] > -1e29f;
                float mnew = fmaxf(mrun[i], mloc[i]);
                float p = keep ? __expf(pe[n][i] - mnew) : 0.f;
                pe[n][i] = p;
                psum[i] += p;
            }
#pragma unroll
        for (int i = 0; i < 4; ++i) {
            psum[i] += __shfl_xor(psum[i], 1, 16);
            psum[i] += __shfl_xor(psum[i], 2, 16);
            psum[i] += __shfl_xor(psum[i], 4, 16);
            psum[i] += __shfl_xor(psum[i], 8, 16);
            float mnew = fmaxf(mrun[i], mloc[i]);
            float scale = __expf(mrun[i] - mnew);
            lrun[i] = lrun[i] * scale + psum[i];
            mrun[i] = mnew;
#pragma unroll
            for (int n = 0; n < 4; ++n) oacc[n][i] *= scale;
        }
#pragma unroll
        for (int n = 0; n < 4; ++n)
#pragma unroll
            for (int i = 0; i < 4; ++i)
                Ps[wave * 16 + l4 * 4 + i][n * 16 + l15] = f2bf(pe[n][i]);
        __syncthreads();

        v8s pa0 = *(const v8s*)&Ps[wave * 16 + l15][l4 * 8];
        v8s pa1 = *(const v8s*)&Ps[wave * 16 + l15][32 + l4 * 8];
#pragma unroll
        for (int n = 0; n < 4; ++n) {
            v8s vb0 = *(const v8s*)&VT[n * 16 + l15][l4 * 8];
            v8s vb1 = *(const v8s*)&VT[n * 16 + l15][32 + l4 * 8];
            oacc[n] = __builtin_amdgcn_mfma_f32_16x16x32_bf16(pa0, vb0, oacc[n], 0, 0, 0);
            oacc[n] = __builtin_amdgcn_mfma_f32_16x16x32_bf16(pa1, vb1, oacc[n], 0, 0, 0);
        }
    }
    float invl[4];
#pragma unroll
    for (int i = 0; i < 4; ++i) invl[i] = lrun[i] > 0.f ? 1.f / lrun[i] : 0.f;
#pragma unroll
    for (int n = 0; n < 4; ++n)
#pragma unroll
        for (int i = 0; i < 4; ++i) {
            int r = wave * 16 + l4 * 4 + i;
            size_t off = ((size_t)b * SS + q0 + r) * DD + h * HDIM + n * 16 + l15;
            ctxbf[off] = f2bf(oacc[n][i] * invl[i]);
        }
}

// ---------------------------------------------------------------------------
extern "C" void kernel_launch(void* const* d_in, const int* in_sizes, int n_in,
                              void* d_out, int out_size, void* d_ws, size_t ws_size,
                              hipStream_t stream) {
    const float* hs = (const float*)d_in[0];
    const float* tf = (const float*)d_in[1];
    const float* Wq = (const float*)d_in[2];
    const float* Wk = (const float*)d_in[3];
    const float* Wv = (const float*)d_in[4];
    const float* Wo = (const float*)d_in[5];
    const float* bo = (const float*)d_in[6];
    const float* Wg = (const float*)d_in[7];
    const float* bg = (const float*)d_in[8];
    const float* hp = (const float*)d_in[9];
    const float* tb = (const float*)d_in[10];
    const int* msk  = (const int*)d_in[11];
    float* out = (float*)d_out;

    char* w = (char*)d_ws;
    short* qkvbf  = (short*)(w + OFF_QBF);
    short* hsbf   = (short*)(w + OFF_HSBF);
    short* tfbf   = (short*)(w + OFF_TFBF);
    short* ctxbf  = (short*)(w + OFF_CTXBF);
    short* ctx2bf = (short*)(w + OFF_CTX2BF);
    short* wtqkv  = (short*)(w + OFF_WTQKV);
    short* wgT    = (short*)(w + OFF_WGT);
    short* woT    = (short*)(w + OFF_WOT);
    short* hpwT   = (short*)(w + OFF_HPWT);
    unsigned long long* codes = (unsigned long long*)(w + OFF_CODES);
    unsigned long long* keepA = (unsigned long long*)(w + OFF_KEEP);
    unsigned int* cmask = (unsigned int*)(w + OFF_CMASK);

    // 1. fused preprocessing (conv + weight transposes + hpwT + cmask zero)
    prep<<<dim3(5216), 256, 0, stream>>>(
        hs, tf, Wq, Wk, Wv, Wg, Wo, hp,
        hsbf, tfbf, wtqkv, wgT, woT, hpwT, cmask);
    // 2. FUSED QKV + proj-with-sign-pack, EXACTLY 512 blocks (one round):
    //    bx 0-11: QKV -> bf16 [B,H,S,HD] x3;  bx 12-15: proj BN=128 -> codes
    gemm_mfma<2, 3><<<dim3(16, 32), 256, 0, stream>>>(
        hsbf, tfbf, wtqkv, hpwT, tb, nullptr, qkvbf, codes,
        512, 768, 128, 3, nullptr, nullptr);
    // 3-4. masks, attention
    mask_kernel<<<dim3(32, 32, 2), 256, 0, stream>>>(codes, msk, keepA, cmask);
    attn_kernel<<<dim3(32, 24), 256, 0, stream>>>(
        qkvbf, qkvbf + 3145728, qkvbf + 2 * 3145728, keepA, cmask, ctxbf);
    // 5. gate GEMM + sigmoid-blend (bf16 inputs) -> ctx2 bf16
    gemm_mfma<2, 1><<<dim3(12, 32), 256, 0, stream>>>(
        ctxbf, tfbf, wgT, nullptr, bg, nullptr, ctx2bf, nullptr,
        768, 768, 128, 2, ctxbf, hsbf);
    // 6. output projection -> d_out f32
    gemm_mfma<2, 1><<<dim3(12, 32), 256, 0, stream>>>(
        ctx2bf, nullptr, woT, nullptr, bo, out, nullptr, nullptr,
        768, 768, 0, 0, nullptr, nullptr);
}

// Round 13
// 94.449 us; speedup vs baseline: 1.4370x; 1.1013x over previous
//
#include <hip/hip_runtime.h>

typedef __attribute__((ext_vector_type(4))) float v4f;
typedef __attribute__((ext_vector_type(8))) short v8s;

// Problem constants
#define BB 2
#define SS 2048
#define DD 768
#define HH 12
#define HDIM 64
#define NWORDS 8          // 512 hash bits = 8 u64
#define HAM_MAX 179       // sim > 0.3  <=>  hamming <= 179

// ws layout (bytes)
#define OFF_QBF    ((size_t)0)             // q,k,v bf16 contiguous 3x6291456
#define OFF_HSBF   ((size_t)31457280)      // 6291456
#define OFF_TFBF   ((size_t)37748736)      // 1048576
#define OFF_CTXBF  ((size_t)38797312)      // 6291456
#define OFF_CTX2BF ((size_t)45088768)      // 6291456
#define OFF_WTQKV  ((size_t)51380224)      // 3538944
#define OFF_WGT    ((size_t)54919168)      // 1376256
#define OFF_WOT    ((size_t)56295424)      // 1179648
#define OFF_HPWT   ((size_t)57475072)      // 917504
#define OFF_CODES  ((size_t)66781184)      // 262144
#define OFF_KEEP   ((size_t)67043328)      // 1048576
#define OFF_CMASK  ((size_t)68091904)      // 256

__device__ inline short f2bf(float x) {
    unsigned u = __float_as_uint(x);
    u = (u + 0x7FFFu + ((u >> 16) & 1u)) >> 16;  // RNE
    return (short)u;
}
__device__ inline float bf2f(short s) {
    return __uint_as_float(((unsigned)(unsigned short)s) << 16);
}

// async global->LDS, 16B per lane, wave-uniform LDS base + lane*16
__device__ __forceinline__ void load_lds16(const void* g, void* l) {
    __builtin_amdgcn_global_load_lds((const __attribute__((address_space(1))) void*)g,
                                     (__attribute__((address_space(3))) void*)l,
                                     16, 0, 0);
}

// ---------------------------------------------------------------------------
// Fused preprocessing: one dispatch, block-range routing.
__global__ __launch_bounds__(256) void prep(
    const float* __restrict__ hs, const float* __restrict__ tf,
    const float* __restrict__ Wq, const float* __restrict__ Wk,
    const float* __restrict__ Wv, const float* __restrict__ Wg,
    const float* __restrict__ Wo, const float* __restrict__ hp,
    short* __restrict__ hsbf, short* __restrict__ tfbf,
    short* __restrict__ wtqkv, short* __restrict__ wgT,
    short* __restrict__ woT, short* __restrict__ hpwT,
    unsigned int* __restrict__ cmask) {
    __shared__ float T[32][33];
    const int blk = blockIdx.x;
    const int tid = threadIdx.x;
    if (blk < 1792) {
        if (blk == 0 && tid < 64) cmask[tid] = 0u;
        int i = blk * 256 + tid;
        const int na8 = 3145728 / 8;
        const float* src; short* dst; int off;
        if (i < na8) { src = hs; dst = hsbf; off = i << 3; }
        else         { src = tf; dst = tfbf; off = (i - na8) << 3; }
        float4 x = *(const float4*)(src + off);
        float4 y = *(const float4*)(src + off + 4);
        v8s r;
        r[0] = f2bf(x.x); r[1] = f2bf(x.y); r[2] = f2bf(x.z); r[3] = f2bf(x.w);
        r[4] = f2bf(y.x); r[5] = f2bf(y.y); r[6] = f2bf(y.z); r[7] = f2bf(y.w);
        *(v8s*)(dst + off) = r;
        return;
    }
    const int tx = tid & 31, ty = tid >> 5;
    if (blk < 3520) {
        int b = blk - 1792;
        int z = b / 576, rem = b % 576;
        int x = rem % 24, y = rem / 24;
        const float* W = (z == 0) ? Wq : (z == 1) ? Wk : Wv;
        short* Wt = wtqkv + (size_t)z * 589824;
        int n0 = x * 32, k0 = y * 32;
#pragma unroll
        for (int p = 0; p < 4; ++p) {
            int kk = ty + p * 8;
            T[tx][kk] = W[(size_t)(k0 + kk) * 768 + n0 + tx];
        }
        __syncthreads();
#pragma unroll
        for (int p = 0; p < 4; ++p) {
            int nn = ty + p * 8;
            Wt[(size_t)(n0 + nn) * 768 + k0 + tx] = f2bf(T[nn][tx]);
        }
    } else if (blk < 4192) {
        int b = blk - 3520;
        int x = b % 24, y = b / 24;
        int n0 = x * 32, k0 = y * 32;
#pragma unroll
        for (int p = 0; p < 4; ++p) {
            int kk = ty + p * 8;
            T[tx][kk] = Wg[(size_t)(k0 + kk) * 768 + n0 + tx];
        }
        __syncthreads();
#pragma unroll
        for (int p = 0; p < 4; ++p) {
            int nn = ty + p * 8;
            wgT[(size_t)(n0 + nn) * 896 + k0 + tx] = f2bf(T[nn][tx]);
        }
    } else if (blk < 4768) {
        int b = blk - 4192;
        int x = b % 24, y = b / 24;
        int n0 = x * 32, k0 = y * 32;
#pragma unroll
        for (int p = 0; p < 4; ++p) {
            int kk = ty + p * 8;
            T[tx][kk] = Wo[(size_t)(k0 + kk) * 768 + n0 + tx];
        }
        __syncthreads();
#pragma unroll
        for (int p = 0; p < 4; ++p) {
            int nn = ty + p * 8;
            woT[(size_t)(n0 + nn) * 768 + k0 + tx] = f2bf(T[nn][tx]);
        }
    } else {
        int b = blk - 4768;
        int x = b % 28, y = b / 28;
        int kk0 = x * 32, hc0 = y * 32;
        int h = hc0 >> 6, cb = hc0 & 63;
#pragma unroll
        for (int p = 0; p < 4; ++p) {
            int kp = ty + p * 8;
            int gk = kk0 + kp;
            int ks = (gk >= 768) ? gk - 768 : gk;
            float f = hp[((size_t)h * 768 + ks) * 64 + cb + tx];
            T[tx][kp] = (gk >= 768) ? 0.1f * f : f;
        }
        __syncthreads();
#pragma unroll
        for (int p = 0; p < 4; ++p) {
            int cp = ty + p * 8;
            hpwT[(size_t)(hc0 + cp) * 896 + kk0 + tx] = f2bf(T[cp][tx]);
        }
    }
}

// ---------------------------------------------------------------------------
// MFMA bf16 GEMM, 2-phase prefetch double-buffer + XCD swizzle.
// Template: WN = 16-col fragments per wave in N; NW = B-slots sharing one
// A-stage; MF = 16-row fragments per wave in M (BM = MF*32).
// mode 3 (grid 16x32 = 512 blocks = 2/CU, single round):
//   bx<12 : fused QKV (nWact=3), K=768 -> LDS-staged COALESCED bf16 stores
//           (each w's 128x64 tile = one contiguous 16KB region of qkv)
//   bx>=12: proj BN=128 (2 halves), K=896 -> sign-pack to codes
// mode 2/0 (MF=2, grid 12x64 = 768 blocks = 3/CU, perfectly packed round).
// Linear LDS + global_load_lds(16) + XOR source-pre-swizzle (conflict-free,
// verified r5-r12: SQ_LDS_BANK_CONFLICT ~ 0).
template<int WN, int NW, int MF>
__global__ __launch_bounds__(256) void gemm_mfma(
    const short* __restrict__ A, const short* __restrict__ A2,
    const short* __restrict__ Bt, const short* __restrict__ Bt2,
    const float* __restrict__ bias,
    float* __restrict__ outF, short* __restrict__ outB,
    unsigned long long* __restrict__ codesOut,
    int N, int K1, int K2, int mode,
    const short* __restrict__ gctxb, const short* __restrict__ ghsb) {
    constexpr int BN = WN * 32;
    constexpr int BM = MF * 32;
    __shared__ __align__(16) short As[2 * BM * 64];
    __shared__ __align__(16) short Bs[2 * NW * BN * 64];
    const int t = threadIdx.x;
    const int lane = t & 63, wave = t >> 6;
    const int wm = wave >> 1, wn = wave & 1;
    const int l15 = lane & 15, l4 = lane >> 4;

    // XCD-aware bijective swizzle (gridDim.y % 8 == 0, blocks % 8 == 0)
    const int nbx = gridDim.x;
    const int perXcd = gridDim.y >> 3;
    int flat = blockIdx.x + nbx * blockIdx.y;
    int xcd = flat & 7, j = flat >> 3;
    int by = xcd * perXcd + j / nbx;
    int bx = j % nbx;
    const int row0 = by * BM;

    // per-block routing
    int nWact, col0, myMode, Kblk;
    const short* Bp;
    const float* biasp = bias;
    if (mode == 3) {
        if (bx < 12) { nWact = NW; col0 = bx * 64;         myMode = 1; Kblk = K1;      Bp = Bt;  biasp = nullptr; }
        else         { nWact = 2;  col0 = (bx - 12) * 128; myMode = 0; Kblk = K1 + K2; Bp = Bt2; }
    } else {
        nWact = 1; col0 = bx * BN; myMode = mode; Kblk = K1 + K2; Bp = Bt;
    }
    const bool sepW = (myMode == 1);

    // source swizzle: lane covers row (chunk*8 + lane>>3), 16B slot (lane&7)
    const int lrow = lane >> 3;
    const int scolS = ((lane & 7) ^ lrow) << 3;

    auto STAGE = [&](int buf, int k0) {
        const short* Ap; int ks, strideS;
        if (k0 < K1) { Ap = A;  ks = k0;      strideS = K1; }
        else         { Ap = A2; ks = k0 - K1; strideS = K2; }
#pragma unroll
        for (int qq = 0; qq < MF; ++qq) {
            int c = wave * MF + qq;                  // A chunk: rows 8c..8c+7
            const short* ga = Ap + (size_t)(row0 + c * 8 + lrow) * strideS + ks + scolS;
            load_lds16(ga, (char*)As + buf * (BM * 128) + c * 1024);
        }
#pragma unroll
        for (int w = 0; w < NW; ++w) {
            if (w < nWact) {
#pragma unroll
                for (int qq = 0; qq < WN; ++qq) {
                    int c = wave * WN + qq;          // B chunk
                    size_t rowIdx = (size_t)(col0 + (sepW ? 0 : w * 64) + c * 8 + lrow);
                    const short* gb = Bp + (sepW ? (size_t)w * 589824 : (size_t)0) +
                                      rowIdx * Kblk + k0 + scolS;
                    load_lds16(gb, (char*)Bs + (buf * NW + w) * (BN * 128) + c * 1024);
                }
            }
        }
    };

    v4f acc[NW][MF][WN];
#pragma unroll
    for (int w = 0; w < NW; ++w)
#pragma unroll
        for (int m = 0; m < MF; ++m)
#pragma unroll
            for (int n = 0; n < WN; ++n) acc[w][m][n] = (v4f){0.f, 0.f, 0.f, 0.f};

    const int nK = Kblk >> 6;
    STAGE(0, 0);
    __syncthreads();
    int cur = 0;
    for (int kt = 0; kt < nK; ++kt) {
        if (kt + 1 < nK) STAGE(cur ^ 1, (kt + 1) << 6);
#pragma unroll
        for (int kk = 0; kk < 2; ++kk) {
            v8s a[MF];
#pragma unroll
            for (int m = 0; m < MF; ++m) {
                int row = wm * (MF * 16) + m * 16 + l15;
                int byte = (row * 128 + kk * 64 + l4 * 16) ^ ((row & 7) << 4);
                a[m] = *(const v8s*)((const char*)As + cur * (BM * 128) + byte);
            }
#pragma unroll
            for (int w = 0; w < NW; ++w) {
                if (w < nWact) {
                    v8s b[WN];
#pragma unroll
                    for (int n = 0; n < WN; ++n) {
                        int row = wn * (WN * 16) + n * 16 + l15;
                        int byte = (row * 128 + kk * 64 + l4 * 16) ^ ((row & 7) << 4);
                        b[n] = *(const v8s*)((const char*)Bs + (cur * NW + w) * (BN * 128) + byte);
                    }
#pragma unroll
                    for (int m = 0; m < MF; ++m)
#pragma unroll
                        for (int n = 0; n < WN; ++n)
                            acc[w][m][n] = __builtin_amdgcn_mfma_f32_16x16x32_bf16(a[m], b[n], acc[w][m][n], 0, 0, 0);
                }
            }
        }
        __syncthreads();
        cur ^= 1;
    }

    // ---- proj epilogue: sign-pack 2 code words straight to codes ----
    if (mode == 3 && myMode == 0) {
        unsigned short* pieces = (unsigned short*)As;  // [128 rows][8 parts]
#pragma unroll
        for (int w = 0; w < 2; ++w)
#pragma unroll
            for (int m = 0; m < MF; ++m)
#pragma unroll
                for (int n = 0; n < WN; ++n) {
                    int gc = col0 + w * 64 + (wn * WN + n) * 16 + l15;
                    int part = w * 4 + wn * WN + n;
#pragma unroll
                    for (int i = 0; i < 4; ++i) {
                        float c = acc[w][m][n][i] + biasp[gc];
                        unsigned long long bal = __ballot(c > 0.f);
                        if (lane < 4) {
                            int rloc = wm * (MF * 16) + m * 16 + lane * 4 + i;
                            pieces[rloc * 8 + part] = (unsigned short)(bal >> (lane * 16));
                        }
                    }
                }
        __syncthreads();
        if (t < 256) {
            int row = t >> 1, word = t & 1;
            const unsigned short* pp = pieces + row * 8 + word * 4;
            unsigned long long w64 = (unsigned long long)pp[0]
                | ((unsigned long long)pp[1] << 16)
                | ((unsigned long long)pp[2] << 32)
                | ((unsigned long long)pp[3] << 48);
            codesOut[(size_t)(row0 + row) * NWORDS + ((col0 >> 6) + word)] = w64;
        }
        return;
    }

    // ---- QKV epilogue: LDS-staged, fully coalesced contiguous stores ----
    if (myMode == 1) {
        short* stg = (short*)As;   // BM x 64 bf16 tile = 16 KB (As is dead)
        const int hh = col0 >> 6;
        const int bb = row0 >> 11;
        const int s0 = row0 & 2047;
#pragma unroll
        for (int w = 0; w < NW; ++w) {
            if (w < nWact) {
                __syncthreads();   // prior copy-out (or K-loop reads) done
#pragma unroll
                for (int m = 0; m < MF; ++m)
#pragma unroll
                    for (int n = 0; n < WN; ++n) {
                        int r = wm * (MF * 16) + m * 16 + l4 * 4;
                        int c = (wn * WN + n) * 16 + l15;
#pragma unroll
                        for (int i = 0; i < 4; ++i)
                            stg[(r + i) * 64 + c] = f2bf(acc[w][m][n][i]);
                    }
                __syncthreads();
                // [bb,hh,s0:s0+BM,0:64] is contiguous: BM*128 bytes
                short* dst = outB + (size_t)w * 3145728 +
                             (((size_t)(bb * HH + hh)) * SS + s0) * HDIM;
                const char* src = (const char*)stg + t * (BM / 2);
                char* d = (char*)dst + t * (BM / 2);
#pragma unroll
                for (int q = 0; q < BM / 32; ++q)
                    *(int4*)(d + q * 16) = *(const int4*)(src + q * 16);
            }
        }
        return;
    }

#pragma unroll
    for (int m = 0; m < MF; ++m) {
#pragma unroll
        for (int n = 0; n < WN; ++n) {
            int gr0 = row0 + (wm * MF + m) * 16 + l4 * 4;
            int gc = col0 + (wn * WN + n) * 16 + l15;
#pragma unroll
            for (int i = 0; i < 4; ++i) {
                int gr = gr0 + i;
                if (myMode == 0) {
                    float c = acc[0][m][n][i];
                    if (biasp) c += biasp[gc];
                    outF[(size_t)gr * N + gc] = c;
                } else {
                    float c = acc[0][m][n][i] + biasp[gc];
                    float g = 1.f / (1.f + __expf(-c));
                    size_t off = (size_t)gr * N + gc;
                    float cv = bf2f(gctxb[off]);
                    float hv = bf2f(ghsb[off]);
                    outB[off] = f2bf(g * cv + (1.f - g) * hv);
                }
            }
        }
    }
}

// ---------------------------------------------------------------------------
// LSH keep masks: one (qchunk, kchunk, b) tile per block, 2048 blocks.
__global__ __launch_bounds__(256) void mask_kernel(
    const unsigned long long* __restrict__ codes, const int* __restrict__ mask,
    unsigned long long* __restrict__ keepArr, unsigned int* __restrict__ chunkmask) {
    __shared__ unsigned long long ckS[64][NWORDS];
    __shared__ int mskS[64];
    const int t = threadIdx.x;
    const int r = t >> 2, tx = t & 3;
    const int qc = blockIdx.x, kc = blockIdx.y, b = blockIdx.z;
    const int q0 = qc << 6, k0 = kc << 6;

#pragma unroll
    for (int p = 0; p < 2; ++p) {
        int idx = t + (p << 8);
        int jr = idx >> 3, ww = idx & 7;
        ckS[jr][ww ^ (jr >> 4)] =
            codes[((size_t)(b * SS + k0 + jr)) * NWORDS + ww];
    }
    if (t < 64) mskS[t] = mask[b * SS + k0 + t];
    unsigned long long cq[NWORDS];
    {
        const unsigned long long* cp = codes + ((size_t)(b * SS + q0 + r)) * NWORDS;
#pragma unroll
        for (int w = 0; w < NWORDS; ++w) cq[w] = cp[w];
    }
    __syncthreads();

    unsigned long long k64 = 0;
#pragma unroll
    for (int j16 = 0; j16 < 16; ++j16) {
        int j = (tx << 4) + j16;
        int ham = 0;
#pragma unroll
        for (int w = 0; w < NWORDS; ++w)
            ham += __popcll(cq[w] ^ ckS[j][w ^ tx]);
        if (ham <= HAM_MAX && mskS[j]) k64 |= 1ull << j;
    }
    k64 |= __shfl_xor(k64, 1, 4);
    k64 |= __shfl_xor(k64, 2, 4);
    if (tx == 0) keepArr[((size_t)(b * SS + q0 + r)) * 32 + kc] = k64;
    if (__syncthreads_or(k64 != 0) && t == 0)
        atomicOr(&chunkmask[b * 32 + qc], 1u << kc);
}

// ---------------------------------------------------------------------------
// MFMA flash attention over active chunks only. bf16 Q/K/V -> bf16 ctx.
__global__ __launch_bounds__(256) void attn_kernel(
    const short* __restrict__ qm, const short* __restrict__ km,
    const short* __restrict__ vm, const unsigned long long* __restrict__ keepArr,
    const unsigned int* __restrict__ chunkmask, short* __restrict__ ctxbf) {
    __shared__ __align__(16) short Qs[64][72];
    __shared__ __align__(16) short Ks[64][72];
    __shared__ __align__(16) short VT[64][72];   // V transposed: [dim][key]
    __shared__ __align__(16) short Ps[64][72];
    __shared__ unsigned long long keepS[64];
    const int t = threadIdx.x;
    const int lane = t & 63, wave = t >> 6;
    const int l15 = lane & 15, l4 = lane >> 4;
    const int q0 = blockIdx.x << 6;
    const int bh = blockIdx.y;
    const int b = bh / HH, h = bh % HH;

    {   // stage Q
        int r = t >> 2, seg = t & 3;
        const short* g = qm + ((size_t)bh * SS + q0 + r) * HDIM + seg * 16;
        *(int4*)&Qs[r][seg * 16] = *(const int4*)g;
        *(int4*)&Qs[r][seg * 16 + 8] = *(const int4*)(g + 8);
    }
    unsigned int cm = chunkmask[b * 32 + blockIdx.x];
    float mrun[4], lrun[4];
    v4f oacc[4];
#pragma unroll
    for (int i = 0; i < 4; ++i) { mrun[i] = -1e30f; lrun[i] = 0.f; }
#pragma unroll
    for (int n = 0; n < 4; ++n) oacc[n] = (v4f){0.f, 0.f, 0.f, 0.f};

    while (cm) {
        int kc = __ffs(cm) - 1;
        cm &= cm - 1;
        __syncthreads();
        if (t < 64) keepS[t] = keepArr[((size_t)(b * SS + q0 + t)) * 32 + kc];
        {   // stage K rows + V transposed
            int key = t >> 2, seg = t & 3;
            const short* gk = km + ((size_t)bh * SS + (kc << 6) + key) * HDIM + seg * 16;
            *(int4*)&Ks[key][seg * 16] = *(const int4*)gk;
            *(int4*)&Ks[key][seg * 16 + 8] = *(const int4*)(gk + 8);
            const short* gv = vm + ((size_t)bh * SS + (kc << 6) + key) * HDIM + seg * 16;
            int4 v0 = *(const int4*)gv, v1 = *(const int4*)(gv + 8);
            const short* s0 = (const short*)&v0;
            const short* s1 = (const short*)&v1;
#pragma unroll
            for (int e = 0; e < 8; ++e) VT[seg * 16 + e][key] = s0[e];
#pragma unroll
            for (int e = 0; e < 8; ++e) VT[seg * 16 + 8 + e][key] = s1[e];
        }
        __syncthreads();

        v8s qa0 = *(const v8s*)&Qs[wave * 16 + l15][l4 * 8];
        v8s qa1 = *(const v8s*)&Qs[wave * 16 + l15][32 + l4 * 8];
        v4f sacc[4];
#pragma unroll
        for (int n = 0; n < 4; ++n) sacc[n] = (v4f){0.f, 0.f, 0.f, 0.f};
#pragma unroll
        for (int n = 0; n < 4; ++n) {
            v8s kb0 = *(const v8s*)&Ks[n * 16 + l15][l4 * 8];
            v8s kb1 = *(const v8s*)&Ks[n * 16 + l15][32 + l4 * 8];
            sacc[n] = __builtin_amdgcn_mfma_f32_16x16x32_bf16(qa0, kb0, sacc[n], 0, 0, 0);
            sacc[n] = __builtin_amdgcn_mfma_f32_16x16x32_bf16(qa1, kb1, sacc[n], 0, 0, 0);
        }
        unsigned long long kp[4];
#pragma unroll
        for (int i = 0; i < 4; ++i) kp[i] = keepS[wave * 16 + l4 * 4 + i];
        float pe[4][4], mloc[4];
#pragma unroll
        for (int i = 0; i < 4; ++i) mloc[i] = -1e30f;
#pragma unroll
        for (int n = 0; n < 4; ++n)
#pragma unroll
            for (int i = 0; i < 4; ++i) {
                bool keep = (kp[i] >> (n * 16 + l15)) & 1;
                float sv = keep ? sacc[n][i] * 0.125f : -1e30f;
                pe[n][i] = sv;
                mloc[i] = fmaxf(mloc[i], sv);
            }
#pragma unroll
        for (int i = 0; i < 4; ++i) {
            mloc[i] = fmaxf(mloc[i], __shfl_xor(mloc[i], 1, 16));
            mloc[i] = fmaxf(mloc[i], __shfl_xor(mloc[i], 2, 16));
            mloc[i] = fmaxf(mloc[i], __shfl_xor(mloc[i], 4, 16));
            mloc[i] = fmaxf(mloc[i], __shfl_xor(mloc[i], 8, 16));
        }
        float psum[4] = {0.f, 0.f, 0.f, 0.f};
#pragma unroll
        for (int n = 0; n < 4; ++n)
#pragma unroll
            for (int i = 0; i < 4; ++i) {
                bool keep = pe[n][i] > -1e29f;
                float mnew = fmaxf(mrun[i], mloc[i]);
                float p = keep ? __expf(pe[n][i] - mnew) : 0.f;
                pe[n][i] = p;
                psum[i] += p;
            }
#pragma unroll
        for (int i = 0; i < 4; ++i) {
            psum[i] += __shfl_xor(psum[i], 1, 16);
            psum[i] += __shfl_xor(psum[i], 2, 16);
            psum[i] += __shfl_xor(psum[i], 4, 16);
            psum[i] += __shfl_xor(psum[i], 8, 16);
            float mnew = fmaxf(mrun[i], mloc[i]);
            float scale = __expf(mrun[i] - mnew);
            lrun[i] = lrun[i] * scale + psum[i];
            mrun[i] = mnew;
#pragma unroll
            for (int n = 0; n < 4; ++n) oacc[n][i] *= scale;
        }
#pragma unroll
        for (int n = 0; n < 4; ++n)
#pragma unroll
            for (int i = 0; i < 4; ++i)
                Ps[wave * 16 + l4 * 4 + i][n * 16 + l15] = f2bf(pe[n][i]);
        __syncthreads();

        v8s pa0 = *(const v8s*)&Ps[wave * 16 + l15][l4 * 8];
        v8s pa1 = *(const v8s*)&Ps[wave * 16 + l15][32 + l4 * 8];
#pragma unroll
        for (int n = 0; n < 4; ++n) {
            v8s vb0 = *(const v8s*)&VT[n * 16 + l15][l4 * 8];
            v8s vb1 = *(const v8s*)&VT[n * 16 + l15][32 + l4 * 8];
            oacc[n] = __builtin_amdgcn_mfma_f32_16x16x32_bf16(pa0, vb0, oacc[n], 0, 0, 0);
            oacc[n] = __builtin_amdgcn_mfma_f32_16x16x32_bf16(pa1, vb1, oacc[n], 0, 0, 0);
        }
    }
    float invl[4];
#pragma unroll
    for (int i = 0; i < 4; ++i) invl[i] = lrun[i] > 0.f ? 1.f / lrun[i] : 0.f;
#pragma unroll
    for (int n = 0; n < 4; ++n)
#pragma unroll
        for (int i = 0; i < 4; ++i) {
            int r = wave * 16 + l4 * 4 + i;
            size_t off = ((size_t)b * SS + q0 + r) * DD + h * HDIM + n * 16 + l15;
            ctxbf[off] = f2bf(oacc[n][i] * invl[i]);
        }
}

// ---------------------------------------------------------------------------
extern "C" void kernel_launch(void* const* d_in, const int* in_sizes, int n_in,
                              void* d_out, int out_size, void* d_ws, size_t ws_size,
                              hipStream_t stream) {
    const float* hs = (const float*)d_in[0];
    const float* tf = (const float*)d_in[1];
    const float* Wq = (const float*)d_in[2];
    const float* Wk = (const float*)d_in[3];
    const float* Wv = (const float*)d_in[4];
    const float* Wo = (const float*)d_in[5];
    const float* bo = (const float*)d_in[6];
    const float* Wg = (const float*)d_in[7];
    const float* bg = (const float*)d_in[8];
    const float* hp = (const float*)d_in[9];
    const float* tb = (const float*)d_in[10];
    const int* msk  = (const int*)d_in[11];
    float* out = (float*)d_out;

    char* w = (char*)d_ws;
    short* qkvbf  = (short*)(w + OFF_QBF);
    short* hsbf   = (short*)(w + OFF_HSBF);
    short* tfbf   = (short*)(w + OFF_TFBF);
    short* ctxbf  = (short*)(w + OFF_CTXBF);
    short* ctx2bf = (short*)(w + OFF_CTX2BF);
    short* wtqkv  = (short*)(w + OFF_WTQKV);
    short* wgT    = (short*)(w + OFF_WGT);
    short* woT    = (short*)(w + OFF_WOT);
    short* hpwT   = (short*)(w + OFF_HPWT);
    unsigned long long* codes = (unsigned long long*)(w + OFF_CODES);
    unsigned long long* keepA = (unsigned long long*)(w + OFF_KEEP);
    unsigned int* cmask = (unsigned int*)(w + OFF_CMASK);

    // 1. fused preprocessing (conv + weight transposes + hpwT + cmask zero)
    prep<<<dim3(5216), 256, 0, stream>>>(
        hs, tf, Wq, Wk, Wv, Wg, Wo, hp,
        hsbf, tfbf, wtqkv, wgT, woT, hpwT, cmask);
    // 2. FUSED QKV + proj-with-sign-pack, 512 blocks (one round, 2/CU)
    gemm_mfma<2, 3, 4><<<dim3(16, 32), 256, 0, stream>>>(
        hsbf, tfbf, wtqkv, hpwT, tb, nullptr, qkvbf, codes,
        512, 768, 128, 3, nullptr, nullptr);
    // 3-4. masks, attention
    mask_kernel<<<dim3(32, 32, 2), 256, 0, stream>>>(codes, msk, keepA, cmask);
    attn_kernel<<<dim3(32, 24), 256, 0, stream>>>(
        qkvbf, qkvbf + 3145728, qkvbf + 2 * 3145728, keepA, cmask, ctxbf);
    // 5. gate GEMM + sigmoid-blend -> ctx2 bf16 (BM=64, 768 blocks = 3/CU)
    gemm_mfma<2, 1, 2><<<dim3(12, 64), 256, 0, stream>>>(
        ctxbf, tfbf, wgT, nullptr, bg, nullptr, ctx2bf, nullptr,
        768, 768, 128, 2, ctxbf, hsbf);
    // 6. output projection -> d_out f32 (BM=64, 768 blocks = 3/CU)
    gemm_mfma<2, 1, 2><<<dim3(12, 64), 256, 0, stream>>>(
        ctx2bf, nullptr, woT, nullptr, bo, out, nullptr, nullptr,
        768, 768, 0, 0, nullptr, nullptr);
}

// Round 14
// 93.481 us; speedup vs baseline: 1.4518x; 1.0104x over previous
//
#include <hip/hip_runtime.h>

typedef __attribute__((ext_vector_type(4))) float v4f;
typedef __attribute__((ext_vector_type(8))) short v8s;

// Problem constants
#define BB 2
#define SS 2048
#define DD 768
#define HH 12
#define HDIM 64
#define NWORDS 8          // 512 hash bits = 8 u64
#define HAM_MAX 179       // sim > 0.3  <=>  hamming <= 179

// ws layout (bytes)
#define OFF_QBF    ((size_t)0)             // q,k,v bf16 contiguous 3x6291456
#define OFF_HSBF   ((size_t)31457280)      // 6291456
#define OFF_TFBF   ((size_t)37748736)      // 1048576
#define OFF_CTXBF  ((size_t)38797312)      // 6291456
#define OFF_CTX2BF ((size_t)45088768)      // 6291456
#define OFF_WTQKV  ((size_t)51380224)      // 3538944
#define OFF_WGT    ((size_t)54919168)      // 1376256
#define OFF_WOT    ((size_t)56295424)      // 1179648
#define OFF_HPWT   ((size_t)57475072)      // 917504
#define OFF_CODES  ((size_t)66781184)      // 262144
#define OFF_KEEP   ((size_t)67043328)      // 1048576
#define OFF_CMASK  ((size_t)68091904)      // 256

__device__ inline short f2bf(float x) {
    unsigned u = __float_as_uint(x);
    u = (u + 0x7FFFu + ((u >> 16) & 1u)) >> 16;  // RNE
    return (short)u;
}
__device__ inline float bf2f(short s) {
    return __uint_as_float(((unsigned)(unsigned short)s) << 16);
}

// async global->LDS, 16B per lane, wave-uniform LDS base + lane*16
__device__ __forceinline__ void load_lds16(const void* g, void* l) {
    __builtin_amdgcn_global_load_lds((const __attribute__((address_space(1))) void*)g,
                                     (__attribute__((address_space(3))) void*)l,
                                     16, 0, 0);
}

// ---------------------------------------------------------------------------
// Fused preprocessing: one dispatch, block-range routing.
__global__ __launch_bounds__(256) void prep(
    const float* __restrict__ hs, const float* __restrict__ tf,
    const float* __restrict__ Wq, const float* __restrict__ Wk,
    const float* __restrict__ Wv, const float* __restrict__ Wg,
    const float* __restrict__ Wo, const float* __restrict__ hp,
    short* __restrict__ hsbf, short* __restrict__ tfbf,
    short* __restrict__ wtqkv, short* __restrict__ wgT,
    short* __restrict__ woT, short* __restrict__ hpwT,
    unsigned int* __restrict__ cmask) {
    __shared__ float T[32][33];
    const int blk = blockIdx.x;
    const int tid = threadIdx.x;
    if (blk < 1792) {
        if (blk == 0 && tid < 64) cmask[tid] = 0u;
        int i = blk * 256 + tid;
        const int na8 = 3145728 / 8;
        const float* src; short* dst; int off;
        if (i < na8) { src = hs; dst = hsbf; off = i << 3; }
        else         { src = tf; dst = tfbf; off = (i - na8) << 3; }
        float4 x = *(const float4*)(src + off);
        float4 y = *(const float4*)(src + off + 4);
        v8s r;
        r[0] = f2bf(x.x); r[1] = f2bf(x.y); r[2] = f2bf(x.z); r[3] = f2bf(x.w);
        r[4] = f2bf(y.x); r[5] = f2bf(y.y); r[6] = f2bf(y.z); r[7] = f2bf(y.w);
        *(v8s*)(dst + off) = r;
        return;
    }
    const int tx = tid & 31, ty = tid >> 5;
    if (blk < 3520) {
        int b = blk - 1792;
        int z = b / 576, rem = b % 576;
        int x = rem % 24, y = rem / 24;
        const float* W = (z == 0) ? Wq : (z == 1) ? Wk : Wv;
        short* Wt = wtqkv + (size_t)z * 589824;
        int n0 = x * 32, k0 = y * 32;
#pragma unroll
        for (int p = 0; p < 4; ++p) {
            int kk = ty + p * 8;
            T[tx][kk] = W[(size_t)(k0 + kk) * 768 + n0 + tx];
        }
        __syncthreads();
#pragma unroll
        for (int p = 0; p < 4; ++p) {
            int nn = ty + p * 8;
            Wt[(size_t)(n0 + nn) * 768 + k0 + tx] = f2bf(T[nn][tx]);
        }
    } else if (blk < 4192) {
        int b = blk - 3520;
        int x = b % 24, y = b / 24;
        int n0 = x * 32, k0 = y * 32;
#pragma unroll
        for (int p = 0; p < 4; ++p) {
            int kk = ty + p * 8;
            T[tx][kk] = Wg[(size_t)(k0 + kk) * 768 + n0 + tx];
        }
        __syncthreads();
#pragma unroll
        for (int p = 0; p < 4; ++p) {
            int nn = ty + p * 8;
            wgT[(size_t)(n0 + nn) * 896 + k0 + tx] = f2bf(T[nn][tx]);
        }
    } else if (blk < 4768) {
        int b = blk - 4192;
        int x = b % 24, y = b / 24;
        int n0 = x * 32, k0 = y * 32;
#pragma unroll
        for (int p = 0; p < 4; ++p) {
            int kk = ty + p * 8;
            T[tx][kk] = Wo[(size_t)(k0 + kk) * 768 + n0 + tx];
        }
        __syncthreads();
#pragma unroll
        for (int p = 0; p < 4; ++p) {
            int nn = ty + p * 8;
            woT[(size_t)(n0 + nn) * 768 + k0 + tx] = f2bf(T[nn][tx]);
        }
    } else {
        int b = blk - 4768;
        int x = b % 28, y = b / 28;
        int kk0 = x * 32, hc0 = y * 32;
        int h = hc0 >> 6, cb = hc0 & 63;
#pragma unroll
        for (int p = 0; p < 4; ++p) {
            int kp = ty + p * 8;
            int gk = kk0 + kp;
            int ks = (gk >= 768) ? gk - 768 : gk;
            float f = hp[((size_t)h * 768 + ks) * 64 + cb + tx];
            T[tx][kp] = (gk >= 768) ? 0.1f * f : f;
        }
        __syncthreads();
#pragma unroll
        for (int p = 0; p < 4; ++p) {
            int cp = ty + p * 8;
            hpwT[(size_t)(hc0 + cp) * 896 + kk0 + tx] = f2bf(T[cp][tx]);
        }
    }
}

// ---------------------------------------------------------------------------
// MFMA bf16 GEMM, 2-phase prefetch double-buffer + XCD swizzle (r13, frozen).
template<int WN, int NW, int MF>
__global__ __launch_bounds__(256) void gemm_mfma(
    const short* __restrict__ A, const short* __restrict__ A2,
    const short* __restrict__ Bt, const short* __restrict__ Bt2,
    const float* __restrict__ bias,
    float* __restrict__ outF, short* __restrict__ outB,
    unsigned long long* __restrict__ codesOut,
    int N, int K1, int K2, int mode,
    const short* __restrict__ gctxb, const short* __restrict__ ghsb) {
    constexpr int BN = WN * 32;
    constexpr int BM = MF * 32;
    __shared__ __align__(16) short As[2 * BM * 64];
    __shared__ __align__(16) short Bs[2 * NW * BN * 64];
    const int t = threadIdx.x;
    const int lane = t & 63, wave = t >> 6;
    const int wm = wave >> 1, wn = wave & 1;
    const int l15 = lane & 15, l4 = lane >> 4;

    const int nbx = gridDim.x;
    const int perXcd = gridDim.y >> 3;
    int flat = blockIdx.x + nbx * blockIdx.y;
    int xcd = flat & 7, j = flat >> 3;
    int by = xcd * perXcd + j / nbx;
    int bx = j % nbx;
    const int row0 = by * BM;

    int nWact, col0, myMode, Kblk;
    const short* Bp;
    const float* biasp = bias;
    if (mode == 3) {
        if (bx < 12) { nWact = NW; col0 = bx * 64;         myMode = 1; Kblk = K1;      Bp = Bt;  biasp = nullptr; }
        else         { nWact = 2;  col0 = (bx - 12) * 128; myMode = 0; Kblk = K1 + K2; Bp = Bt2; }
    } else {
        nWact = 1; col0 = bx * BN; myMode = mode; Kblk = K1 + K2; Bp = Bt;
    }
    const bool sepW = (myMode == 1);

    const int lrow = lane >> 3;
    const int scolS = ((lane & 7) ^ lrow) << 3;

    auto STAGE = [&](int buf, int k0) {
        const short* Ap; int ks, strideS;
        if (k0 < K1) { Ap = A;  ks = k0;      strideS = K1; }
        else         { Ap = A2; ks = k0 - K1; strideS = K2; }
#pragma unroll
        for (int qq = 0; qq < MF; ++qq) {
            int c = wave * MF + qq;
            const short* ga = Ap + (size_t)(row0 + c * 8 + lrow) * strideS + ks + scolS;
            load_lds16(ga, (char*)As + buf * (BM * 128) + c * 1024);
        }
#pragma unroll
        for (int w = 0; w < NW; ++w) {
            if (w < nWact) {
#pragma unroll
                for (int qq = 0; qq < WN; ++qq) {
                    int c = wave * WN + qq;
                    size_t rowIdx = (size_t)(col0 + (sepW ? 0 : w * 64) + c * 8 + lrow);
                    const short* gb = Bp + (sepW ? (size_t)w * 589824 : (size_t)0) +
                                      rowIdx * Kblk + k0 + scolS;
                    load_lds16(gb, (char*)Bs + (buf * NW + w) * (BN * 128) + c * 1024);
                }
            }
        }
    };

    v4f acc[NW][MF][WN];
#pragma unroll
    for (int w = 0; w < NW; ++w)
#pragma unroll
        for (int m = 0; m < MF; ++m)
#pragma unroll
            for (int n = 0; n < WN; ++n) acc[w][m][n] = (v4f){0.f, 0.f, 0.f, 0.f};

    const int nK = Kblk >> 6;
    STAGE(0, 0);
    __syncthreads();
    int cur = 0;
    for (int kt = 0; kt < nK; ++kt) {
        if (kt + 1 < nK) STAGE(cur ^ 1, (kt + 1) << 6);
#pragma unroll
        for (int kk = 0; kk < 2; ++kk) {
            v8s a[MF];
#pragma unroll
            for (int m = 0; m < MF; ++m) {
                int row = wm * (MF * 16) + m * 16 + l15;
                int byte = (row * 128 + kk * 64 + l4 * 16) ^ ((row & 7) << 4);
                a[m] = *(const v8s*)((const char*)As + cur * (BM * 128) + byte);
            }
#pragma unroll
            for (int w = 0; w < NW; ++w) {
                if (w < nWact) {
                    v8s b[WN];
#pragma unroll
                    for (int n = 0; n < WN; ++n) {
                        int row = wn * (WN * 16) + n * 16 + l15;
                        int byte = (row * 128 + kk * 64 + l4 * 16) ^ ((row & 7) << 4);
                        b[n] = *(const v8s*)((const char*)Bs + (cur * NW + w) * (BN * 128) + byte);
                    }
#pragma unroll
                    for (int m = 0; m < MF; ++m)
#pragma unroll
                        for (int n = 0; n < WN; ++n)
                            acc[w][m][n] = __builtin_amdgcn_mfma_f32_16x16x32_bf16(a[m], b[n], acc[w][m][n], 0, 0, 0);
                }
            }
        }
        __syncthreads();
        cur ^= 1;
    }

    // ---- proj epilogue: sign-pack 2 code words straight to codes ----
    if (mode == 3 && myMode == 0) {
        unsigned short* pieces = (unsigned short*)As;
#pragma unroll
        for (int w = 0; w < 2; ++w)
#pragma unroll
            for (int m = 0; m < MF; ++m)
#pragma unroll
                for (int n = 0; n < WN; ++n) {
                    int gc = col0 + w * 64 + (wn * WN + n) * 16 + l15;
                    int part = w * 4 + wn * WN + n;
#pragma unroll
                    for (int i = 0; i < 4; ++i) {
                        float c = acc[w][m][n][i] + biasp[gc];
                        unsigned long long bal = __ballot(c > 0.f);
                        if (lane < 4) {
                            int rloc = wm * (MF * 16) + m * 16 + lane * 4 + i;
                            pieces[rloc * 8 + part] = (unsigned short)(bal >> (lane * 16));
                        }
                    }
                }
        __syncthreads();
        if (t < 256) {
            int row = t >> 1, word = t & 1;
            const unsigned short* pp = pieces + row * 8 + word * 4;
            unsigned long long w64 = (unsigned long long)pp[0]
                | ((unsigned long long)pp[1] << 16)
                | ((unsigned long long)pp[2] << 32)
                | ((unsigned long long)pp[3] << 48);
            codesOut[(size_t)(row0 + row) * NWORDS + ((col0 >> 6) + word)] = w64;
        }
        return;
    }

    // ---- QKV epilogue: LDS-staged, fully coalesced contiguous stores ----
    if (myMode == 1) {
        short* stg = (short*)As;
        const int hh = col0 >> 6;
        const int bb = row0 >> 11;
        const int s0 = row0 & 2047;
#pragma unroll
        for (int w = 0; w < NW; ++w) {
            if (w < nWact) {
                __syncthreads();
#pragma unroll
                for (int m = 0; m < MF; ++m)
#pragma unroll
                    for (int n = 0; n < WN; ++n) {
                        int r = wm * (MF * 16) + m * 16 + l4 * 4;
                        int c = (wn * WN + n) * 16 + l15;
#pragma unroll
                        for (int i = 0; i < 4; ++i)
                            stg[(r + i) * 64 + c] = f2bf(acc[w][m][n][i]);
                    }
                __syncthreads();
                short* dst = outB + (size_t)w * 3145728 +
                             (((size_t)(bb * HH + hh)) * SS + s0) * HDIM;
                const char* src = (const char*)stg + t * (BM / 2);
                char* d = (char*)dst + t * (BM / 2);
#pragma unroll
                for (int q = 0; q < BM / 32; ++q)
                    *(int4*)(d + q * 16) = *(const int4*)(src + q * 16);
            }
        }
        return;
    }

#pragma unroll
    for (int m = 0; m < MF; ++m) {
#pragma unroll
        for (int n = 0; n < WN; ++n) {
            int gr0 = row0 + (wm * MF + m) * 16 + l4 * 4;
            int gc = col0 + (wn * WN + n) * 16 + l15;
#pragma unroll
            for (int i = 0; i < 4; ++i) {
                int gr = gr0 + i;
                if (myMode == 0) {
                    float c = acc[0][m][n][i];
                    if (biasp) c += biasp[gc];
                    outF[(size_t)gr * N + gc] = c;
                } else {
                    float c = acc[0][m][n][i] + biasp[gc];
                    float g = 1.f / (1.f + __expf(-c));
                    size_t off = (size_t)gr * N + gc;
                    float cv = bf2f(gctxb[off]);
                    float hv = bf2f(ghsb[off]);
                    outB[off] = f2bf(g * cv + (1.f - g) * hv);
                }
            }
        }
    }
}

// ---------------------------------------------------------------------------
// LSH keep masks v3: SYMMETRIC — only upper-triangle (qc<=kc) chunk pairs,
// 528 x 2 blocks (was 1024 x 2). sim(q,k)=sim(k,q) within a batch; the
// mirror entry is produced by a 64x64 bit transpose through LDS. Pad mask
// applies to the KEY side only, so transpose the PRE-mask hamming bits and
// AND with the q-chunk pad bits for the mirrored direction.
__global__ __launch_bounds__(256) void mask_kernel(
    const unsigned long long* __restrict__ codes, const int* __restrict__ mask,
    unsigned long long* __restrict__ keepArr, unsigned int* __restrict__ chunkmask) {
    __shared__ unsigned long long ckS[64][NWORDS];
    __shared__ unsigned long long rowBits[64];   // pre-mask hamming bits per q-row
    __shared__ unsigned long long maskW[2];      // [0]=k-chunk pad bits, [1]=q-chunk
    const int t = threadIdx.x;
    const int r = t >> 2, tx = t & 3;
    // triangular decode: blockIdx.x -> (qc, kc) with qc <= kc
    int i = blockIdx.x, qc = 0;
    while (i >= 32 - qc) { i -= 32 - qc; ++qc; }
    const int kc = qc + i;
    const int b = blockIdx.y;
    const int q0 = qc << 6, k0 = kc << 6;

    // stage key codes (word-slot XOR swizzle, matches hamming read pattern)
#pragma unroll
    for (int p = 0; p < 2; ++p) {
        int idx = t + (p << 8);
        int jr = idx >> 3, ww = idx & 7;
        ckS[jr][ww ^ (jr >> 4)] =
            codes[((size_t)(b * SS + k0 + jr)) * NWORDS + ww];
    }
    // pad-bit ballots: wave0 -> k-chunk bits, wave1 -> q-chunk bits
    if (t < 64) {
        unsigned long long bm = __ballot(mask[b * SS + k0 + (t & 63)] != 0);
        if (t == 0) maskW[0] = bm;
    } else if (t < 128) {
        unsigned long long bm = __ballot(mask[b * SS + q0 + (t & 63)] != 0);
        if ((t & 63) == 0) maskW[1] = bm;
    }
    // own q-row codes -> regs
    unsigned long long cq[NWORDS];
    {
        const unsigned long long* cp = codes + ((size_t)(b * SS + q0 + r)) * NWORDS;
#pragma unroll
        for (int w = 0; w < NWORDS; ++w) cq[w] = cp[w];
    }
    __syncthreads();

    unsigned long long kham = 0;
#pragma unroll
    for (int j16 = 0; j16 < 16; ++j16) {
        int j = (tx << 4) + j16;
        int ham = 0;
#pragma unroll
        for (int w = 0; w < NWORDS; ++w)
            ham += __popcll(cq[w] ^ ckS[j][w ^ tx]);
        if (ham <= HAM_MAX) kham |= 1ull << j;
    }
    kham |= __shfl_xor(kham, 1, 4);
    kham |= __shfl_xor(kham, 2, 4);
    unsigned long long k64 = kham & maskW[0];
    if (tx == 0) {
        keepArr[((size_t)(b * SS + q0 + r)) * 32 + kc] = k64;
        rowBits[r] = kham;
    }
    bool any1 = __syncthreads_or(k64 != 0);   // also fences rowBits writes

    unsigned long long t64 = 0;
    if (kc != qc) {
        // transpose: thread group (r=j) assembles bit q of every rowBits[q]
#pragma unroll
        for (int qq = 0; qq < 16; ++qq) {
            int q = (tx << 4) + qq;
            t64 |= ((rowBits[q] >> r) & 1ull) << q;
        }
        t64 |= __shfl_xor(t64, 1, 4);
        t64 |= __shfl_xor(t64, 2, 4);
        t64 &= maskW[1];
        if (tx == 0)
            keepArr[((size_t)(b * SS + k0 + r)) * 32 + qc] = t64;
    }
    bool any2 = __syncthreads_or(t64 != 0);
    if (t == 0) {
        if (any1) atomicOr(&chunkmask[b * 32 + qc], 1u << kc);
        if (any2) atomicOr(&chunkmask[b * 32 + kc], 1u << qc);
    }
}

// ---------------------------------------------------------------------------
// MFMA flash attention over active chunks only. bf16 Q/K/V -> bf16 ctx.
// T5: s_setprio(1) around MFMA clusters (m191: helps attn-like structures).
__global__ __launch_bounds__(256) void attn_kernel(
    const short* __restrict__ qm, const short* __restrict__ km,
    const short* __restrict__ vm, const unsigned long long* __restrict__ keepArr,
    const unsigned int* __restrict__ chunkmask, short* __restrict__ ctxbf) {
    __shared__ __align__(16) short Qs[64][72];
    __shared__ __align__(16) short Ks[64][72];
    __shared__ __align__(16) short VT[64][72];   // V transposed: [dim][key]
    __shared__ __align__(16) short Ps[64][72];
    __shared__ unsigned long long keepS[64];
    const int t = threadIdx.x;
    const int lane = t & 63, wave = t >> 6;
    const int l15 = lane & 15, l4 = lane >> 4;
    const int q0 = blockIdx.x << 6;
    const int bh = blockIdx.y;
    const int b = bh / HH, h = bh % HH;

    {   // stage Q
        int r = t >> 2, seg = t & 3;
        const short* g = qm + ((size_t)bh * SS + q0 + r) * HDIM + seg * 16;
        *(int4*)&Qs[r][seg * 16] = *(const int4*)g;
        *(int4*)&Qs[r][seg * 16 + 8] = *(const int4*)(g + 8);
    }
    unsigned int cm = chunkmask[b * 32 + blockIdx.x];
    float mrun[4], lrun[4];
    v4f oacc[4];
#pragma unroll
    for (int i = 0; i < 4; ++i) { mrun[i] = -1e30f; lrun[i] = 0.f; }
#pragma unroll
    for (int n = 0; n < 4; ++n) oacc[n] = (v4f){0.f, 0.f, 0.f, 0.f};

    while (cm) {
        int kc = __ffs(cm) - 1;
        cm &= cm - 1;
        __syncthreads();
        if (t < 64) keepS[t] = keepArr[((size_t)(b * SS + q0 + t)) * 32 + kc];
        {   // stage K rows + V transposed
            int key = t >> 2, seg = t & 3;
            const short* gk = km + ((size_t)bh * SS + (kc << 6) + key) * HDIM + seg * 16;
            *(int4*)&Ks[key][seg * 16] = *(const int4*)gk;
            *(int4*)&Ks[key][seg * 16 + 8] = *(const int4*)(gk + 8);
            const short* gv = vm + ((size_t)bh * SS + (kc << 6) + key) * HDIM + seg * 16;
            int4 v0 = *(const int4*)gv, v1 = *(const int4*)(gv + 8);
            const short* s0 = (const short*)&v0;
            const short* s1 = (const short*)&v1;
#pragma unroll
            for (int e = 0; e < 8; ++e) VT[seg * 16 + e][key] = s0[e];
#pragma unroll
            for (int e = 0; e < 8; ++e) VT[seg * 16 + 8 + e][key] = s1[e];
        }
        __syncthreads();

        v8s qa0 = *(const v8s*)&Qs[wave * 16 + l15][l4 * 8];
        v8s qa1 = *(const v8s*)&Qs[wave * 16 + l15][32 + l4 * 8];
        v4f sacc[4];
#pragma unroll
        for (int n = 0; n < 4; ++n) sacc[n] = (v4f){0.f, 0.f, 0.f, 0.f};
        __builtin_amdgcn_s_setprio(1);
#pragma unroll
        for (int n = 0; n < 4; ++n) {
            v8s kb0 = *(const v8s*)&Ks[n * 16 + l15][l4 * 8];
            v8s kb1 = *(const v8s*)&Ks[n * 16 + l15][32 + l4 * 8];
            sacc[n] = __builtin_amdgcn_mfma_f32_16x16x32_bf16(qa0, kb0, sacc[n], 0, 0, 0);
            sacc[n] = __builtin_amdgcn_mfma_f32_16x16x32_bf16(qa1, kb1, sacc[n], 0, 0, 0);
        }
        __builtin_amdgcn_s_setprio(0);
        unsigned long long kp[4];
#pragma unroll
        for (int i = 0; i < 4; ++i) kp[i] = keepS[wave * 16 + l4 * 4 + i];
        float pe[4][4], mloc[4];
#pragma unroll
        for (int i = 0; i < 4; ++i) mloc[i] = -1e30f;
#pragma unroll
        for (int n = 0; n < 4; ++n)
#pragma unroll
            for (int i = 0; i < 4; ++i) {
                bool keep = (kp[i] >> (n * 16 + l15)) & 1;
                float sv = keep ? sacc[n][i] * 0.125f : -1e30f;
                pe[n][i] = sv;
                mloc[i] = fmaxf(mloc[i], sv);
            }
#pragma unroll
        for (int i = 0; i < 4; ++i) {
            mloc[i] = fmaxf(mloc[i], __shfl_xor(mloc[i], 1, 16));
            mloc[i] = fmaxf(mloc[i], __shfl_xor(mloc[i], 2, 16));
            mloc[i] = fmaxf(mloc[i], __shfl_xor(mloc[i], 4, 16));
            mloc[i] = fmaxf(mloc[i], __shfl_xor(mloc[i], 8, 16));
        }
        float psum[4] = {0.f, 0.f, 0.f, 0.f};
#pragma unroll
        for (int n = 0; n < 4; ++n)
#pragma unroll
            for (int i = 0; i < 4; ++i) {
                bool keep = pe[n][i] > -1e29f;
                float mnew = fmaxf(mrun[i], mloc[i]);
                float p = keep ? __expf(pe[n][i] - mnew) : 0.f;
                pe[n][i] = p;
                psum[i] += p;
            }
#pragma unroll
        for (int i = 0; i < 4; ++i) {
            psum[i] += __shfl_xor(psum[i], 1, 16);
            psum[i] += __shfl_xor(psum[i], 2, 16);
            psum[i] += __shfl_xor(psum[i], 4, 16);
            psum[i] += __shfl_xor(psum[i], 8, 16);
            float mnew = fmaxf(mrun[i], mloc[i]);
            float scale = __expf(mrun[i] - mnew);
            lrun[i] = lrun[i] * scale + psum[i];
            mrun[i] = mnew;
#pragma unroll
            for (int n = 0; n < 4; ++n) oacc[n][i] *= scale;
        }
#pragma unroll
        for (int n = 0; n < 4; ++n)
#pragma unroll
            for (int i = 0; i < 4; ++i)
                Ps[wave * 16 + l4 * 4 + i][n * 16 + l15] = f2bf(pe[n][i]);
        __syncthreads();

        v8s pa0 = *(const v8s*)&Ps[wave * 16 + l15][l4 * 8];
        v8s pa1 = *(const v8s*)&Ps[wave * 16 + l15][32 + l4 * 8];
        __builtin_amdgcn_s_setprio(1);
#pragma unroll
        for (int n = 0; n < 4; ++n) {
            v8s vb0 = *(const v8s*)&VT[n * 16 + l15][l4 * 8];
            v8s vb1 = *(const v8s*)&VT[n * 16 + l15][32 + l4 * 8];
            oacc[n] = __builtin_amdgcn_mfma_f32_16x16x32_bf16(pa0, vb0, oacc[n], 0, 0, 0);
            oacc[n] = __builtin_amdgcn_mfma_f32_16x16x32_bf16(pa1, vb1, oacc[n], 0, 0, 0);
        }
        __builtin_amdgcn_s_setprio(0);
    }
    float invl[4];
#pragma unroll
    for (int i = 0; i < 4; ++i) invl[i] = lrun[i] > 0.f ? 1.f / lrun[i] : 0.f;
#pragma unroll
    for (int n = 0; n < 4; ++n)
#pragma unroll
        for (int i = 0; i < 4; ++i) {
            int r = wave * 16 + l4 * 4 + i;
            size_t off = ((size_t)b * SS + q0 + r) * DD + h * HDIM + n * 16 + l15;
            ctxbf[off] = f2bf(oacc[n][i] * invl[i]);
        }
}

// ---------------------------------------------------------------------------
extern "C" void kernel_launch(void* const* d_in, const int* in_sizes, int n_in,
                              void* d_out, int out_size, void* d_ws, size_t ws_size,
                              hipStream_t stream) {
    const float* hs = (const float*)d_in[0];
    const float* tf = (const float*)d_in[1];
    const float* Wq = (const float*)d_in[2];
    const float* Wk = (const float*)d_in[3];
    const float* Wv = (const float*)d_in[4];
    const float* Wo = (const float*)d_in[5];
    const float* bo = (const float*)d_in[6];
    const float* Wg = (const float*)d_in[7];
    const float* bg = (const float*)d_in[8];
    const float* hp = (const float*)d_in[9];
    const float* tb = (const float*)d_in[10];
    const int* msk  = (const int*)d_in[11];
    float* out = (float*)d_out;

    char* w = (char*)d_ws;
    short* qkvbf  = (short*)(w + OFF_QBF);
    short* hsbf   = (short*)(w + OFF_HSBF);
    short* tfbf   = (short*)(w + OFF_TFBF);
    short* ctxbf  = (short*)(w + OFF_CTXBF);
    short* ctx2bf = (short*)(w + OFF_CTX2BF);
    short* wtqkv  = (short*)(w + OFF_WTQKV);
    short* wgT    = (short*)(w + OFF_WGT);
    short* woT    = (short*)(w + OFF_WOT);
    short* hpwT   = (short*)(w + OFF_HPWT);
    unsigned long long* codes = (unsigned long long*)(w + OFF_CODES);
    unsigned long long* keepA = (unsigned long long*)(w + OFF_KEEP);
    unsigned int* cmask = (unsigned int*)(w + OFF_CMASK);

    // 1. fused preprocessing (conv + weight transposes + hpwT + cmask zero)
    prep<<<dim3(5216), 256, 0, stream>>>(
        hs, tf, Wq, Wk, Wv, Wg, Wo, hp,
        hsbf, tfbf, wtqkv, wgT, woT, hpwT, cmask);
    // 2. FUSED QKV + proj-with-sign-pack, 512 blocks (one round, 2/CU)
    gemm_mfma<2, 3, 4><<<dim3(16, 32), 256, 0, stream>>>(
        hsbf, tfbf, wtqkv, hpwT, tb, nullptr, qkvbf, codes,
        512, 768, 128, 3, nullptr, nullptr);
    // 3-4. masks (symmetric upper-triangle), attention
    mask_kernel<<<dim3(528, 2), 256, 0, stream>>>(codes, msk, keepA, cmask);
    attn_kernel<<<dim3(32, 24), 256, 0, stream>>>(
        qkvbf, qkvbf + 3145728, qkvbf + 2 * 3145728, keepA, cmask, ctxbf);
    // 5. gate GEMM + sigmoid-blend -> ctx2 bf16 (BM=64, 768 blocks = 3/CU)
    gemm_mfma<2, 1, 2><<<dim3(12, 64), 256, 0, stream>>>(
        ctxbf, tfbf, wgT, nullptr, bg, nullptr, ctx2bf, nullptr,
        768, 768, 128, 2, ctxbf, hsbf);
    // 6. output projection -> d_out f32 (BM=64, 768 blocks = 3/CU)
    gemm_mfma<2, 1, 2><<<dim3(12, 64), 256, 0, stream>>>(
        ctx2bf, nullptr, woT, nullptr, bo, out, nullptr, nullptr,
        768, 768, 0, 0, nullptr, nullptr);
}